// Round 2
// baseline (929.411 us; speedup 1.0000x reference)
//
#include <hip/hip_runtime.h>
#include <hip/hip_bf16.h>
#include <math.h>

// ---------------- JAX threefry2x32 (partitionable) + normal ----------------

static __device__ __forceinline__ unsigned rotl32(unsigned x, int d) {
  return (x << d) | (x >> (32 - d));
}

// key = (0, 42)  == jax.random.key(42)
static __device__ __forceinline__ void threefry_0_42(unsigned& x0, unsigned& x1) {
  const unsigned ks0 = 0u, ks1 = 42u, ks2 = 0u ^ 42u ^ 0x1BD11BDAu;
  x0 += ks0; x1 += ks1;
#define TF_R(r) { x0 += x1; x1 = rotl32(x1, (r)); x1 ^= x0; }
  TF_R(13) TF_R(15) TF_R(26) TF_R(6)
  x0 += ks1; x1 += ks2 + 1u;
  TF_R(17) TF_R(29) TF_R(16) TF_R(24)
  x0 += ks2; x1 += ks0 + 2u;
  TF_R(13) TF_R(15) TF_R(26) TF_R(6)
  x0 += ks0; x1 += ks1 + 3u;
  TF_R(17) TF_R(29) TF_R(16) TF_R(24)
  x0 += ks1; x1 += ks2 + 4u;
  TF_R(13) TF_R(15) TF_R(26) TF_R(6)
  x0 += ks2; x1 += ks0 + 5u;
#undef TF_R
}

static __device__ __forceinline__ float erfinv_f(float u) {
  float w = -logf((1.0f - u) * (1.0f + u));
  float p;
  if (w < 5.0f) {
    w = w - 2.5f;
    p = 2.81022636e-08f;
    p = fmaf(p, w, 3.43273939e-07f);
    p = fmaf(p, w, -3.5233877e-06f);
    p = fmaf(p, w, -4.39150654e-06f);
    p = fmaf(p, w, 0.00021858087f);
    p = fmaf(p, w, -0.00125372503f);
    p = fmaf(p, w, -0.00417768164f);
    p = fmaf(p, w, 0.246640727f);
    p = fmaf(p, w, 1.50140941f);
  } else {
    w = sqrtf(w) - 3.0f;
    p = -0.000200214257f;
    p = fmaf(p, w, 0.000100950558f);
    p = fmaf(p, w, 0.00134934322f);
    p = fmaf(p, w, -0.00367342844f);
    p = fmaf(p, w, 0.00573950773f);
    p = fmaf(p, w, -0.0076224613f);
    p = fmaf(p, w, 0.00943887047f);
    p = fmaf(p, w, 1.00167406f);
    p = fmaf(p, w, 2.83297682f);
  }
  return p * u;
}

// jax_threefry_partitionable=True (modern default):
// bits(j) = xor(threefry2x32(key, (hi32(j), lo32(j))))   [j < 2^32 -> (0, j)]
static __device__ __forceinline__ float jax_normal_at(unsigned j) {
  unsigned x0 = 0u, x1 = j;
  threefry_0_42(x0, x1);
  unsigned bits = x0 ^ x1;
  float f = __uint_as_float((bits >> 9) | 0x3f800000u) - 1.0f;   // [0,1)
  float u = fmaf(f, 1.99999994f, -0.99999994f);                  // [lo, 1)
  return 1.41421356237f * erfinv_f(u);                           // sqrt(2)*erfinv
}

// ---------------- utility kernels ----------------

__global__ void zero_kernel(float* __restrict__ p, int n) {
  int i = blockIdx.x * blockDim.x + threadIdx.x;
  if (i < n) p[i] = 0.0f;
}

__global__ void degree_kernel(const int* __restrict__ dstI, float* __restrict__ deg, int ne) {
  int e = blockIdx.x * blockDim.x + threadIdx.x;
  if (e < ne) atomicAdd(&deg[dstI[e]], 1.0f);
}

// in: A = deg (dst in-degree). out: A = 1/sqrt(deg+1), B = 1/(deg+1)
__global__ void dinv_kernel(float* __restrict__ A, float* __restrict__ B, int n) {
  int i = blockIdx.x * blockDim.x + threadIdx.x;
  if (i < n) {
    float d = A[i] + 1.0f;
    A[i] = 1.0f / sqrtf(d);
    B[i] = 1.0f / d;
  }
}

// ---------------- dense X@W (W staged in LDS) ----------------
template<int IN1, int IN2, int OUT, bool DUALW, int NODES_PER_BLOCK>
__global__ __launch_bounds__(256) void gemm_kernel(
    const float* __restrict__ X1, const float* __restrict__ X2,
    const float* __restrict__ Wa, const float* __restrict__ Wb,
    float* __restrict__ Y, int n) {
  constexpr int IN = IN1 + IN2;
  constexpr int H = OUT / 2;
  __shared__ float wlds[IN * OUT];
  for (int i = threadIdx.x; i < IN * OUT; i += 256) {
    if (DUALW) {
      int k = i / OUT, c = i % OUT;
      wlds[i] = (c < H) ? Wa[k * H + c] : Wb[k * H + (c - H)];
    } else {
      wlds[i] = Wa[i];
    }
  }
  __syncthreads();
  constexpr int NPP = 256 / OUT;  // nodes per pass
  const int col = threadIdx.x % OUT;
  const int nsub = threadIdx.x / OUT;
  const int base = blockIdx.x * NODES_PER_BLOCK;
  for (int p = 0; p < NODES_PER_BLOCK; p += NPP) {
    int node = base + p + nsub;
    if (node < n) {
      float acc = 0.0f;
      const float* x1 = X1 + (size_t)node * IN1;
#pragma unroll
      for (int k = 0; k < IN1; ++k) acc = fmaf(x1[k], wlds[k * OUT + col], acc);
      if (IN2 > 0) {
        const float* x2 = X2 + (size_t)node * IN2;
#pragma unroll
        for (int k = 0; k < IN2; ++k) acc = fmaf(x2[k], wlds[(IN1 + k) * OUT + col], acc);
      }
      Y[(size_t)node * OUT + col] = acc;
    }
  }
}

// ---------------- edge scatter: agg[dst] += xw[src] * dinv[src]*dinv[dst] ----------------
template<int OUT>
__global__ __launch_bounds__(256) void scatter_kernel(
    const int* __restrict__ srcI, const int* __restrict__ dstI,
    const float* __restrict__ dinv, const float* __restrict__ xw,
    float* __restrict__ agg, int ne) {
  int idx = blockIdx.x * blockDim.x + threadIdx.x;
  int e = idx / OUT;
  int col = idx % OUT;
  if (e >= ne) return;
  int s = srcI[e], d = dstI[e];
  float coef = dinv[s] * dinv[d];
  atomicAdd(&agg[(size_t)d * OUT + col], xw[(size_t)s * OUT + col] * coef);
}

// ---------------- finalizers ----------------
template<int OUT>
__global__ void finalize_relu_kernel(float* __restrict__ agg, const float* __restrict__ xw,
                                     const float* __restrict__ invdeg, const float* __restrict__ bias,
                                     float* __restrict__ outp, int n) {
  int idx = blockIdx.x * blockDim.x + threadIdx.x;
  if (idx >= n * OUT) return;
  int node = idx / OUT, col = idx % OUT;
  float v = agg[idx] + xw[idx] * invdeg[node] + bias[col];
  outp[idx] = fmaxf(v, 0.0f);
}

template<int OUT>
__global__ void finalize_kernel(float* __restrict__ agg, const float* __restrict__ xw,
                                const float* __restrict__ invdeg, const float* __restrict__ bias,
                                int n) {
  int idx = blockIdx.x * blockDim.x + threadIdx.x;
  if (idx >= n * OUT) return;
  int node = idx / OUT, col = idx % OUT;
  agg[idx] = agg[idx] + xw[idx] * invdeg[node] + bias[col];
}

// mean/logvar packed as [node][0:32]=mean-part, [32:64]=logvar-part.
// writes z (d_out+0), mean (d_out+n*32), logvar (d_out+2*n*32)
__global__ void finalize_mlv_kernel(const float* __restrict__ agg, const float* __restrict__ xw,
                                    const float* __restrict__ invdeg,
                                    const float* __restrict__ bm, const float* __restrict__ blv,
                                    float* __restrict__ dout, int n) {
  int idx = blockIdx.x * blockDim.x + threadIdx.x;
  if (idx >= n * 64) return;
  int node = idx >> 6, c = idx & 63;
  float b = (c < 32) ? bm[c] : blv[c - 32];
  float v = agg[idx] + xw[idx] * invdeg[node] + b;
  int lane = threadIdx.x & 63;
  float other = __shfl(v, lane ^ 32, 64);
  int NZ = n * 32;
  if (c < 32) {
    int j = node * 32 + c;
    float lv = other;
    float noise = jax_normal_at((unsigned)j);
    dout[j] = fmaf(noise, expf(0.5f * lv), v);  // z
    dout[NZ + j] = v;                           // mean
  } else {
    int j = node * 32 + (c - 32);
    dout[2 * NZ + j] = v;                       // logvar
  }
}

// ---------------- launch ----------------

extern "C" void kernel_launch(void* const* d_in, const int* in_sizes, int n_in,
                              void* d_out, int out_size, void* d_ws, size_t ws_size,
                              hipStream_t stream) {
  const float* feat = (const float*)d_in[0];
  const float* cond = (const float*)d_in[1];
  const int*   eidx = (const int*)d_in[2];
  const float* W1  = (const float*)d_in[3];
  const float* b1  = (const float*)d_in[4];
  const float* Wm  = (const float*)d_in[5];
  const float* bm  = (const float*)d_in[6];
  const float* Wlv = (const float*)d_in[7];
  const float* blv = (const float*)d_in[8];
  const float* Wd  = (const float*)d_in[9];
  const float* bd  = (const float*)d_in[10];
  const float* Wo  = (const float*)d_in[11];
  const float* bo  = (const float*)d_in[12];

  const int n  = in_sizes[0] / 64;   // 50000
  const int ne = in_sizes[2] / 2;    // 800000
  const int* srcI = eidx;
  const int* dstI = eidx + ne;

  float* ws = (float*)d_ws;
  float* A = ws;                       // deg -> dinv   [n]
  float* B = A + n;                    // invdeg        [n]
  float* C = B + n;                    // [n*64] xw scratch
  float* D = C + (size_t)n * 64;       // [n*64] agg1/h, aggd/hd
  float* G = D + (size_t)n * 64;       // [n*64] agg mean||logvar

  float* dout   = (float*)d_out;
  float* zbuf   = dout;                       // n*32
  float* outbuf = dout + (size_t)3 * n * 32;  // n*64

  const int BT = 256;
  auto blk = [](long long t) { return (int)((t + 255) / 256); };
  const int nb_n   = blk(n);
  const int nb_n64 = blk((long long)n * 64);
  const int nb_e   = blk(ne);
  const int nb_e64 = blk((long long)ne * 64);
  const int nb_g   = (n + 15) / 16;

  // degrees
  hipLaunchKernelGGL(zero_kernel, dim3(nb_n), dim3(BT), 0, stream, A, n);
  hipLaunchKernelGGL(degree_kernel, dim3(nb_e), dim3(BT), 0, stream, dstI, A, ne);
  hipLaunchKernelGGL(dinv_kernel, dim3(nb_n), dim3(BT), 0, stream, A, B, n);

  // ---- encoder conv1: h = relu(gcn(concat(feat,cond), W1, b1)) ----
  hipLaunchKernelGGL(zero_kernel, dim3(nb_n64), dim3(BT), 0, stream, D, n * 64);
  hipLaunchKernelGGL((gemm_kernel<64, 32, 64, false, 16>), dim3(nb_g), dim3(BT), 0, stream,
                     feat, cond, W1, nullptr, C, n);
  hipLaunchKernelGGL((scatter_kernel<64>), dim3(nb_e64), dim3(BT), 0, stream,
                     srcI, dstI, A, C, D, ne);
  hipLaunchKernelGGL((finalize_relu_kernel<64>), dim3(nb_n64), dim3(BT), 0, stream,
                     D, C, B, b1, D, n);

  // ---- mean/logvar (packed dual conv) + z ----
  hipLaunchKernelGGL(zero_kernel, dim3(nb_n64), dim3(BT), 0, stream, G, n * 64);
  hipLaunchKernelGGL((gemm_kernel<64, 0, 64, true, 16>), dim3(nb_g), dim3(BT), 0, stream,
                     D, nullptr, Wm, Wlv, C, n);
  hipLaunchKernelGGL((scatter_kernel<64>), dim3(nb_e64), dim3(BT), 0, stream,
                     srcI, dstI, A, C, G, ne);
  hipLaunchKernelGGL(finalize_mlv_kernel, dim3(nb_n64), dim3(BT), 0, stream,
                     G, C, B, bm, blv, dout, n);

  // ---- decoder conv1: hd = relu(gcn(concat(z,cond), Wd, bd)) ----
  hipLaunchKernelGGL(zero_kernel, dim3(nb_n64), dim3(BT), 0, stream, D, n * 64);
  hipLaunchKernelGGL((gemm_kernel<32, 32, 64, false, 16>), dim3(nb_g), dim3(BT), 0, stream,
                     zbuf, cond, Wd, nullptr, C, n);
  hipLaunchKernelGGL((scatter_kernel<64>), dim3(nb_e64), dim3(BT), 0, stream,
                     srcI, dstI, A, C, D, ne);
  hipLaunchKernelGGL((finalize_relu_kernel<64>), dim3(nb_n64), dim3(BT), 0, stream,
                     D, C, B, bd, D, n);

  // ---- decoder out conv ----
  hipLaunchKernelGGL(zero_kernel, dim3(nb_n64), dim3(BT), 0, stream, outbuf, n * 64);
  hipLaunchKernelGGL((gemm_kernel<64, 0, 64, false, 16>), dim3(nb_g), dim3(BT), 0, stream,
                     D, nullptr, Wo, nullptr, C, n);
  hipLaunchKernelGGL((scatter_kernel<64>), dim3(nb_e64), dim3(BT), 0, stream,
                     srcI, dstI, A, C, outbuf, ne);
  hipLaunchKernelGGL((finalize_kernel<64>), dim3(nb_n64), dim3(BT), 0, stream,
                     outbuf, C, B, bo, n);
}

// Round 3
// 447.152 us; speedup vs baseline: 2.0785x; 2.0785x over previous
//
#include <hip/hip_runtime.h>
#include <hip/hip_bf16.h>
#include <math.h>

// ---------------- JAX threefry2x32 (partitionable) + normal ----------------

static __device__ __forceinline__ unsigned rotl32(unsigned x, int d) {
  return (x << d) | (x >> (32 - d));
}

// key = (0, 42)  == jax.random.key(42)
static __device__ __forceinline__ void threefry_0_42(unsigned& x0, unsigned& x1) {
  const unsigned ks0 = 0u, ks1 = 42u, ks2 = 0u ^ 42u ^ 0x1BD11BDAu;
  x0 += ks0; x1 += ks1;
#define TF_R(r) { x0 += x1; x1 = rotl32(x1, (r)); x1 ^= x0; }
  TF_R(13) TF_R(15) TF_R(26) TF_R(6)
  x0 += ks1; x1 += ks2 + 1u;
  TF_R(17) TF_R(29) TF_R(16) TF_R(24)
  x0 += ks2; x1 += ks0 + 2u;
  TF_R(13) TF_R(15) TF_R(26) TF_R(6)
  x0 += ks0; x1 += ks1 + 3u;
  TF_R(17) TF_R(29) TF_R(16) TF_R(24)
  x0 += ks1; x1 += ks2 + 4u;
  TF_R(13) TF_R(15) TF_R(26) TF_R(6)
  x0 += ks2; x1 += ks0 + 5u;
#undef TF_R
}

static __device__ __forceinline__ float erfinv_f(float u) {
  float w = -logf((1.0f - u) * (1.0f + u));
  float p;
  if (w < 5.0f) {
    w = w - 2.5f;
    p = 2.81022636e-08f;
    p = fmaf(p, w, 3.43273939e-07f);
    p = fmaf(p, w, -3.5233877e-06f);
    p = fmaf(p, w, -4.39150654e-06f);
    p = fmaf(p, w, 0.00021858087f);
    p = fmaf(p, w, -0.00125372503f);
    p = fmaf(p, w, -0.00417768164f);
    p = fmaf(p, w, 0.246640727f);
    p = fmaf(p, w, 1.50140941f);
  } else {
    w = sqrtf(w) - 3.0f;
    p = -0.000200214257f;
    p = fmaf(p, w, 0.000100950558f);
    p = fmaf(p, w, 0.00134934322f);
    p = fmaf(p, w, -0.00367342844f);
    p = fmaf(p, w, 0.00573950773f);
    p = fmaf(p, w, -0.0076224613f);
    p = fmaf(p, w, 0.00943887047f);
    p = fmaf(p, w, 1.00167406f);
    p = fmaf(p, w, 2.83297682f);
  }
  return p * u;
}

// jax_threefry_partitionable=True: bits(j) = xor(threefry2x32(key, (0, j)))
static __device__ __forceinline__ float jax_normal_at(unsigned j) {
  unsigned x0 = 0u, x1 = j;
  threefry_0_42(x0, x1);
  unsigned bits = x0 ^ x1;
  float f = __uint_as_float((bits >> 9) | 0x3f800000u) - 1.0f;   // [0,1)
  float u = fmaf(f, 1.99999994f, -0.99999994f);
  return 1.41421356237f * erfinv_f(u);
}

// ---------------- setup kernels ----------------

__global__ void zero_i_kernel(int* __restrict__ p, int n) {
  int i = blockIdx.x * blockDim.x + threadIdx.x;
  if (i < n) p[i] = 0;
}

__global__ void degree_i_kernel(const int* __restrict__ dstI, int* __restrict__ cnt, int ne) {
  int e = blockIdx.x * blockDim.x + threadIdx.x;
  if (e < ne) atomicAdd(&cnt[dstI[e]], 1);
}

__global__ void dinv_kernel(const int* __restrict__ cnt, float* __restrict__ dinv,
                            float* __restrict__ invdeg, int n) {
  int i = blockIdx.x * blockDim.x + threadIdx.x;
  if (i < n) {
    float d = (float)cnt[i] + 1.0f;
    dinv[i] = 1.0f / sqrtf(d);
    invdeg[i] = 1.0f / d;
  }
}

// ---- exclusive scan of cnt[n] -> rowptr (3 kernels, 1024 elems/block) ----
__global__ __launch_bounds__(256) void scan1_kernel(const int* __restrict__ cnt,
                                                    int* __restrict__ rowptr,
                                                    int* __restrict__ bsum, int n) {
  __shared__ int s[256];
  const int t = threadIdx.x;
  const int base = blockIdx.x * 1024 + t * 4;
  int v0 = (base + 0 < n) ? cnt[base + 0] : 0;
  int v1 = (base + 1 < n) ? cnt[base + 1] : 0;
  int v2 = (base + 2 < n) ? cnt[base + 2] : 0;
  int v3 = (base + 3 < n) ? cnt[base + 3] : 0;
  int tot = v0 + v1 + v2 + v3;
  s[t] = tot;
  __syncthreads();
  for (int off = 1; off < 256; off <<= 1) {
    int x = (t >= off) ? s[t - off] : 0;
    __syncthreads();
    s[t] += x;
    __syncthreads();
  }
  int excl = s[t] - tot;
  if (t == 255) bsum[blockIdx.x] = s[t];
  if (base + 0 < n) rowptr[base + 0] = excl;
  if (base + 1 < n) rowptr[base + 1] = excl + v0;
  if (base + 2 < n) rowptr[base + 2] = excl + v0 + v1;
  if (base + 3 < n) rowptr[base + 3] = excl + v0 + v1 + v2;
}

__global__ __launch_bounds__(256) void scanP_kernel(int* __restrict__ bsum,
                                                    int* __restrict__ boff,
                                                    int nb, int* __restrict__ rowptr,
                                                    int n, int ne) {
  __shared__ int s[256];
  const int t = threadIdx.x;
  int v = (t < nb) ? bsum[t] : 0;
  s[t] = v;
  __syncthreads();
  for (int off = 1; off < 256; off <<= 1) {
    int x = (t >= off) ? s[t - off] : 0;
    __syncthreads();
    s[t] += x;
    __syncthreads();
  }
  if (t < nb) boff[t] = s[t] - v;
  if (t == 0) rowptr[n] = ne;
}

// adds block offsets; also zeroes cnt for reuse as fill cursor
__global__ void scan2_kernel(int* __restrict__ rowptr, const int* __restrict__ boff,
                             int* __restrict__ cnt, int n) {
  int i = blockIdx.x * blockDim.x + threadIdx.x;
  if (i < n) {
    rowptr[i] += boff[i >> 10];
    cnt[i] = 0;
  }
}

// counting-sort fill: dst-sorted (src, coef) pairs
__global__ void fill_kernel(const int* __restrict__ srcI, const int* __restrict__ dstI,
                            const float* __restrict__ dinv, const int* __restrict__ rowptr,
                            int* __restrict__ cnt, int* __restrict__ ssrc,
                            float* __restrict__ scoef, int ne) {
  int e = blockIdx.x * blockDim.x + threadIdx.x;
  if (e >= ne) return;
  int s = srcI[e], d = dstI[e];
  int pos = rowptr[d] + atomicAdd(&cnt[d], 1);
  ssrc[pos] = s;
  scoef[pos] = dinv[s] * dinv[d];
}

// ---------------- dense X@W (W staged in LDS) ----------------
template<int IN1, int IN2, int OUT, bool DUALW, int NODES_PER_BLOCK>
__global__ __launch_bounds__(256) void gemm_kernel(
    const float* __restrict__ X1, const float* __restrict__ X2,
    const float* __restrict__ Wa, const float* __restrict__ Wb,
    float* __restrict__ Y, int n) {
  constexpr int IN = IN1 + IN2;
  constexpr int H = OUT / 2;
  __shared__ float wlds[IN * OUT];
  for (int i = threadIdx.x; i < IN * OUT; i += 256) {
    if (DUALW) {
      int k = i / OUT, c = i % OUT;
      wlds[i] = (c < H) ? Wa[k * H + c] : Wb[k * H + (c - H)];
    } else {
      wlds[i] = Wa[i];
    }
  }
  __syncthreads();
  constexpr int NPP = 256 / OUT;
  const int col = threadIdx.x % OUT;
  const int nsub = threadIdx.x / OUT;
  const int base = blockIdx.x * NODES_PER_BLOCK;
  for (int p = 0; p < NODES_PER_BLOCK; p += NPP) {
    int node = base + p + nsub;
    if (node < n) {
      float acc = 0.0f;
      const float* x1 = X1 + (size_t)node * IN1;
#pragma unroll
      for (int k = 0; k < IN1; ++k) acc = fmaf(x1[k], wlds[k * OUT + col], acc);
      if (IN2 > 0) {
        const float* x2 = X2 + (size_t)node * IN2;
#pragma unroll
        for (int k = 0; k < IN2; ++k) acc = fmaf(x2[k], wlds[(IN1 + k) * OUT + col], acc);
      }
      Y[(size_t)node * OUT + col] = acc;
    }
  }
}

// ---------------- CSR gather + fused finalize ----------------
// one wave (64 lanes) per node; lane = column. MODE 0: +bias,relu -> out
// MODE 1: mean||logvar packed; writes z, mean, logvar into dout. MODE 2: +bias -> out
template<int MODE>
__global__ __launch_bounds__(256) void gather_kernel(
    const int* __restrict__ rowptr, const int* __restrict__ ssrc,
    const float* __restrict__ scoef, const float* __restrict__ xw,
    const float* __restrict__ invdeg, const float* __restrict__ b0,
    const float* __restrict__ b1, float* __restrict__ out, int n) {
  const int node = (blockIdx.x * 256 + threadIdx.x) >> 6;
  const int lane = threadIdx.x & 63;
  if (node >= n) return;
  const int beg = rowptr[node];
  const int end = rowptr[node + 1];
  float acc = xw[(size_t)node * 64 + lane] * invdeg[node];
  float acc2 = 0.0f;
  int e = beg;
  for (; e + 1 < end; e += 2) {
    int s0 = ssrc[e], s1 = ssrc[e + 1];
    float c0 = scoef[e], c1 = scoef[e + 1];
    acc  = fmaf(xw[(size_t)s0 * 64 + lane], c0, acc);
    acc2 = fmaf(xw[(size_t)s1 * 64 + lane], c1, acc2);
  }
  if (e < end) acc = fmaf(xw[(size_t)ssrc[e] * 64 + lane], scoef[e], acc);
  acc += acc2;

  if (MODE == 0) {
    out[(size_t)node * 64 + lane] = fmaxf(acc + b0[lane], 0.0f);
  } else if (MODE == 2) {
    out[(size_t)node * 64 + lane] = acc + b0[lane];
  } else {
    // MODE 1: lanes 0..31 = mean cols, 32..63 = logvar cols
    float v = acc + ((lane < 32) ? b0[lane] : b1[lane - 32]);
    float other = __shfl(v, lane ^ 32, 64);
    const int NZ = n * 32;
    if (lane < 32) {
      int j = node * 32 + lane;
      float noise = jax_normal_at((unsigned)j);
      out[j] = fmaf(noise, expf(0.5f * other), v);  // z
      out[NZ + j] = v;                              // mean
    } else {
      out[2 * NZ + node * 32 + (lane - 32)] = v;    // logvar
    }
  }
}

// ---------------- launch ----------------

extern "C" void kernel_launch(void* const* d_in, const int* in_sizes, int n_in,
                              void* d_out, int out_size, void* d_ws, size_t ws_size,
                              hipStream_t stream) {
  const float* feat = (const float*)d_in[0];
  const float* cond = (const float*)d_in[1];
  const int*   eidx = (const int*)d_in[2];
  const float* W1  = (const float*)d_in[3];
  const float* b1  = (const float*)d_in[4];
  const float* Wm  = (const float*)d_in[5];
  const float* bm  = (const float*)d_in[6];
  const float* Wlv = (const float*)d_in[7];
  const float* blv = (const float*)d_in[8];
  const float* Wd  = (const float*)d_in[9];
  const float* bd  = (const float*)d_in[10];
  const float* Wo  = (const float*)d_in[11];
  const float* bo  = (const float*)d_in[12];

  const int n  = in_sizes[0] / 64;   // 50000
  const int ne = in_sizes[2] / 2;    // 800000
  const int* srcI = eidx;
  const int* dstI = eidx + ne;

  // workspace carve-up
  int*   cnt    = (int*)d_ws;              // n
  int*   rowptr = cnt + n;                 // n+1
  int*   bsum   = rowptr + n + 1;          // 256
  int*   boff   = bsum + 256;              // 256
  int*   ssrc   = boff + 256;              // ne
  float* scoef  = (float*)(ssrc + ne);     // ne
  float* dinv   = scoef + ne;              // n
  float* invdeg = dinv + n;                // n
  float* xw     = invdeg + n;              // n*64
  float* h      = xw + (size_t)n * 64;     // n*64

  float* dout   = (float*)d_out;
  float* zbuf   = dout;                        // n*32
  float* outbuf = dout + (size_t)3 * n * 32;   // n*64

  const int BT = 256;
  auto blk = [](long long t) { return (int)((t + 255) / 256); };
  const int nb_n  = blk(n);
  const int nb_e  = blk(ne);
  const int nb_sc = (n + 1023) / 1024;         // scan blocks (<=256)
  const int nb_gw = blk((long long)n * 64);    // wave-per-node grids (n*64 threads)
  const int nb_g  = (n + 15) / 16;             // gemm grid

  // ---- CSR setup ----
  hipLaunchKernelGGL(zero_i_kernel, dim3(nb_n), dim3(BT), 0, stream, cnt, n);
  hipLaunchKernelGGL(degree_i_kernel, dim3(nb_e), dim3(BT), 0, stream, dstI, cnt, ne);
  hipLaunchKernelGGL(dinv_kernel, dim3(nb_n), dim3(BT), 0, stream, cnt, dinv, invdeg, n);
  hipLaunchKernelGGL(scan1_kernel, dim3(nb_sc), dim3(BT), 0, stream, cnt, rowptr, bsum, n);
  hipLaunchKernelGGL(scanP_kernel, dim3(1), dim3(BT), 0, stream, bsum, boff, nb_sc, rowptr, n, ne);
  hipLaunchKernelGGL(scan2_kernel, dim3(nb_n), dim3(BT), 0, stream, rowptr, boff, cnt, n);
  hipLaunchKernelGGL(fill_kernel, dim3(nb_e), dim3(BT), 0, stream,
                     srcI, dstI, dinv, rowptr, cnt, ssrc, scoef, ne);

  // ---- encoder conv1: h = relu(gcn(concat(feat,cond), W1, b1)) ----
  hipLaunchKernelGGL((gemm_kernel<64, 32, 64, false, 16>), dim3(nb_g), dim3(BT), 0, stream,
                     feat, cond, W1, nullptr, xw, n);
  hipLaunchKernelGGL((gather_kernel<0>), dim3(nb_gw), dim3(BT), 0, stream,
                     rowptr, ssrc, scoef, xw, invdeg, b1, nullptr, h, n);

  // ---- mean/logvar packed conv + reparam z ----
  hipLaunchKernelGGL((gemm_kernel<64, 0, 64, true, 16>), dim3(nb_g), dim3(BT), 0, stream,
                     h, nullptr, Wm, Wlv, xw, n);
  hipLaunchKernelGGL((gather_kernel<1>), dim3(nb_gw), dim3(BT), 0, stream,
                     rowptr, ssrc, scoef, xw, invdeg, bm, blv, dout, n);

  // ---- decoder conv1: hd = relu(gcn(concat(z,cond), Wd, bd)) ----
  hipLaunchKernelGGL((gemm_kernel<32, 32, 64, false, 16>), dim3(nb_g), dim3(BT), 0, stream,
                     zbuf, cond, Wd, nullptr, xw, n);
  hipLaunchKernelGGL((gather_kernel<0>), dim3(nb_gw), dim3(BT), 0, stream,
                     rowptr, ssrc, scoef, xw, invdeg, bd, nullptr, h, n);

  // ---- decoder out conv ----
  hipLaunchKernelGGL((gemm_kernel<64, 0, 64, false, 16>), dim3(nb_g), dim3(BT), 0, stream,
                     h, nullptr, Wo, nullptr, xw, n);
  hipLaunchKernelGGL((gather_kernel<2>), dim3(nb_gw), dim3(BT), 0, stream,
                     rowptr, ssrc, scoef, xw, invdeg, bo, nullptr, outbuf, n);
}

// Round 4
// 375.678 us; speedup vs baseline: 2.4740x; 1.1903x over previous
//
#include <hip/hip_runtime.h>
#include <hip/hip_bf16.h>
#include <hip/hip_fp16.h>
#include <math.h>

// ---------------- JAX threefry2x32 (partitionable) + normal ----------------

static __device__ __forceinline__ unsigned rotl32(unsigned x, int d) {
  return (x << d) | (x >> (32 - d));
}

// key = (0, 42)  == jax.random.key(42)
static __device__ __forceinline__ void threefry_0_42(unsigned& x0, unsigned& x1) {
  const unsigned ks0 = 0u, ks1 = 42u, ks2 = 0u ^ 42u ^ 0x1BD11BDAu;
  x0 += ks0; x1 += ks1;
#define TF_R(r) { x0 += x1; x1 = rotl32(x1, (r)); x1 ^= x0; }
  TF_R(13) TF_R(15) TF_R(26) TF_R(6)
  x0 += ks1; x1 += ks2 + 1u;
  TF_R(17) TF_R(29) TF_R(16) TF_R(24)
  x0 += ks2; x1 += ks0 + 2u;
  TF_R(13) TF_R(15) TF_R(26) TF_R(6)
  x0 += ks0; x1 += ks1 + 3u;
  TF_R(17) TF_R(29) TF_R(16) TF_R(24)
  x0 += ks1; x1 += ks2 + 4u;
  TF_R(13) TF_R(15) TF_R(26) TF_R(6)
  x0 += ks2; x1 += ks0 + 5u;
#undef TF_R
}

static __device__ __forceinline__ float erfinv_f(float u) {
  float w = -logf((1.0f - u) * (1.0f + u));
  float p;
  if (w < 5.0f) {
    w = w - 2.5f;
    p = 2.81022636e-08f;
    p = fmaf(p, w, 3.43273939e-07f);
    p = fmaf(p, w, -3.5233877e-06f);
    p = fmaf(p, w, -4.39150654e-06f);
    p = fmaf(p, w, 0.00021858087f);
    p = fmaf(p, w, -0.00125372503f);
    p = fmaf(p, w, -0.00417768164f);
    p = fmaf(p, w, 0.246640727f);
    p = fmaf(p, w, 1.50140941f);
  } else {
    w = sqrtf(w) - 3.0f;
    p = -0.000200214257f;
    p = fmaf(p, w, 0.000100950558f);
    p = fmaf(p, w, 0.00134934322f);
    p = fmaf(p, w, -0.00367342844f);
    p = fmaf(p, w, 0.00573950773f);
    p = fmaf(p, w, -0.0076224613f);
    p = fmaf(p, w, 0.00943887047f);
    p = fmaf(p, w, 1.00167406f);
    p = fmaf(p, w, 2.83297682f);
  }
  return p * u;
}

// jax_threefry_partitionable=True: bits(j) = xor(threefry2x32(key, (0, j)))
static __device__ __forceinline__ float jax_normal_at(unsigned j) {
  unsigned x0 = 0u, x1 = j;
  threefry_0_42(x0, x1);
  unsigned bits = x0 ^ x1;
  float f = __uint_as_float((bits >> 9) | 0x3f800000u) - 1.0f;   // [0,1)
  float u = fmaf(f, 1.99999994f, -0.99999994f);
  return 1.41421356237f * erfinv_f(u);
}

// ---------------- setup kernels ----------------

__global__ void zero_i_kernel(int* __restrict__ p, int n) {
  int i = blockIdx.x * blockDim.x + threadIdx.x;
  if (i < n) p[i] = 0;
}

__global__ void degree_i_kernel(const int* __restrict__ dstI, int* __restrict__ cnt, int ne) {
  int e = blockIdx.x * blockDim.x + threadIdx.x;
  if (e < ne) atomicAdd(&cnt[dstI[e]], 1);
}

// ---- exclusive scan of cnt[n] -> rowptr ----
__global__ __launch_bounds__(256) void scan1_kernel(const int* __restrict__ cnt,
                                                    int* __restrict__ rowptr,
                                                    int* __restrict__ bsum, int n) {
  __shared__ int s[256];
  const int t = threadIdx.x;
  const int base = blockIdx.x * 1024 + t * 4;
  int v0 = (base + 0 < n) ? cnt[base + 0] : 0;
  int v1 = (base + 1 < n) ? cnt[base + 1] : 0;
  int v2 = (base + 2 < n) ? cnt[base + 2] : 0;
  int v3 = (base + 3 < n) ? cnt[base + 3] : 0;
  int tot = v0 + v1 + v2 + v3;
  s[t] = tot;
  __syncthreads();
  for (int off = 1; off < 256; off <<= 1) {
    int x = (t >= off) ? s[t - off] : 0;
    __syncthreads();
    s[t] += x;
    __syncthreads();
  }
  int excl = s[t] - tot;
  if (t == 255) bsum[blockIdx.x] = s[t];
  if (base + 0 < n) rowptr[base + 0] = excl;
  if (base + 1 < n) rowptr[base + 1] = excl + v0;
  if (base + 2 < n) rowptr[base + 2] = excl + v0 + v1;
  if (base + 3 < n) rowptr[base + 3] = excl + v0 + v1 + v2;
}

__global__ __launch_bounds__(256) void scanP_kernel(int* __restrict__ bsum,
                                                    int* __restrict__ boff,
                                                    int nb, int* __restrict__ rowptr,
                                                    int n, int ne) {
  __shared__ int s[256];
  const int t = threadIdx.x;
  int v = (t < nb) ? bsum[t] : 0;
  s[t] = v;
  __syncthreads();
  for (int off = 1; off < 256; off <<= 1) {
    int x = (t >= off) ? s[t - off] : 0;
    __syncthreads();
    s[t] += x;
    __syncthreads();
  }
  if (t < nb) boff[t] = s[t] - v;
  if (t == 0) rowptr[n] = ne;
}

// adds block offsets; computes dinv; zeroes cnt for reuse as fill cursor
__global__ void scan2_kernel(int* __restrict__ rowptr, const int* __restrict__ boff,
                             int* __restrict__ cnt, float* __restrict__ dinv, int n) {
  int i = blockIdx.x * blockDim.x + threadIdx.x;
  if (i < n) {
    rowptr[i] += boff[i >> 10];
    float d = (float)cnt[i] + 1.0f;
    dinv[i] = 1.0f / sqrtf(d);
    cnt[i] = 0;
  }
}

// counting-sort fill: dst-sorted src indices (uint16, n < 65536)
__global__ void fill_kernel(const int* __restrict__ srcI, const int* __restrict__ dstI,
                            const int* __restrict__ rowptr, int* __restrict__ cnt,
                            unsigned short* __restrict__ ssrc, int ne) {
  int e = blockIdx.x * blockDim.x + threadIdx.x;
  if (e >= ne) return;
  int s = srcI[e], d = dstI[e];
  int pos = rowptr[d] + atomicAdd(&cnt[d], 1);
  ssrc[pos] = (unsigned short)s;
}

// ---------------- dense X@W (W staged in LDS), out = half, scaled by dinv[node] ----------------
template<int IN1, int IN2, int OUT, bool DUALW, int NODES_PER_BLOCK>
__global__ __launch_bounds__(256) void gemm_kernel(
    const float* __restrict__ X1, const float* __restrict__ X2,
    const float* __restrict__ Wa, const float* __restrict__ Wb,
    const float* __restrict__ dinv, __half* __restrict__ Y, int n) {
  constexpr int IN = IN1 + IN2;
  constexpr int H = OUT / 2;
  __shared__ float wlds[IN * OUT];
  for (int i = threadIdx.x; i < IN * OUT; i += 256) {
    if (DUALW) {
      int k = i / OUT, c = i % OUT;
      wlds[i] = (c < H) ? Wa[k * H + c] : Wb[k * H + (c - H)];
    } else {
      wlds[i] = Wa[i];
    }
  }
  __syncthreads();
  constexpr int NPP = 256 / OUT;
  const int col = threadIdx.x % OUT;
  const int nsub = threadIdx.x / OUT;
  const int base = blockIdx.x * NODES_PER_BLOCK;
  for (int p = 0; p < NODES_PER_BLOCK; p += NPP) {
    int node = base + p + nsub;
    if (node < n) {
      float acc = 0.0f;
      const float* x1 = X1 + (size_t)node * IN1;
#pragma unroll
      for (int k = 0; k < IN1; ++k) acc = fmaf(x1[k], wlds[k * OUT + col], acc);
      if (IN2 > 0) {
        const float* x2 = X2 + (size_t)node * IN2;
#pragma unroll
        for (int k = 0; k < IN2; ++k) acc = fmaf(x2[k], wlds[(IN1 + k) * OUT + col], acc);
      }
      Y[(size_t)node * OUT + col] = __float2half(acc * dinv[node]);
    }
  }
}

// ---------------- CSR gather + fused finalize ----------------
// one wave per node; lane = column. agg = dinv[d]*(sum_edges xwp[s] + xwp[d])
// MODE 0: +bias, relu -> out. MODE 1: mean||logvar packed -> z/mean/logvar. MODE 2: +bias -> out
template<int MODE>
__global__ __launch_bounds__(256) void gather_kernel(
    const int* __restrict__ rowptr, const unsigned short* __restrict__ ssrc,
    const __half* __restrict__ xwp, const float* __restrict__ dinv,
    const float* __restrict__ b0, const float* __restrict__ b1,
    float* __restrict__ out, int n) {
  const int node = (blockIdx.x * 256 + threadIdx.x) >> 6;
  const int lane = threadIdx.x & 63;
  if (node >= n) return;
  const int beg = rowptr[node];
  const int end = rowptr[node + 1];
  float acc = __half2float(xwp[(size_t)node * 64 + lane]);  // self loop
  float acc2 = 0.0f;
  for (int cbase = beg; cbase < end; cbase += 64) {
    int m = end - cbase; if (m > 64) m = 64;
    unsigned sv = (lane < m) ? (unsigned)ssrc[cbase + lane] : 0u;
    int k = 0;
    for (; k + 1 < m; k += 2) {
      unsigned s0 = __shfl(sv, k, 64);
      unsigned s1 = __shfl(sv, k + 1, 64);
      acc  += __half2float(xwp[(size_t)s0 * 64 + lane]);
      acc2 += __half2float(xwp[(size_t)s1 * 64 + lane]);
    }
    if (k < m) {
      unsigned s0 = __shfl(sv, k, 64);
      acc += __half2float(xwp[(size_t)s0 * 64 + lane]);
    }
  }
  acc = (acc + acc2) * dinv[node];

  if (MODE == 0) {
    out[(size_t)node * 64 + lane] = fmaxf(acc + b0[lane], 0.0f);
  } else if (MODE == 2) {
    out[(size_t)node * 64 + lane] = acc + b0[lane];
  } else {
    // MODE 1: lanes 0..31 = mean cols, 32..63 = logvar cols
    float v = acc + ((lane < 32) ? b0[lane] : b1[lane - 32]);
    float other = __shfl(v, lane ^ 32, 64);
    const int NZ = n * 32;
    if (lane < 32) {
      int j = node * 32 + lane;
      float noise = jax_normal_at((unsigned)j);
      out[j] = fmaf(noise, expf(0.5f * other), v);  // z
      out[NZ + j] = v;                              // mean
    } else {
      out[2 * NZ + node * 32 + (lane - 32)] = v;    // logvar
    }
  }
}

// ---------------- launch ----------------

extern "C" void kernel_launch(void* const* d_in, const int* in_sizes, int n_in,
                              void* d_out, int out_size, void* d_ws, size_t ws_size,
                              hipStream_t stream) {
  const float* feat = (const float*)d_in[0];
  const float* cond = (const float*)d_in[1];
  const int*   eidx = (const int*)d_in[2];
  const float* W1  = (const float*)d_in[3];
  const float* b1  = (const float*)d_in[4];
  const float* Wm  = (const float*)d_in[5];
  const float* bm  = (const float*)d_in[6];
  const float* Wlv = (const float*)d_in[7];
  const float* blv = (const float*)d_in[8];
  const float* Wd  = (const float*)d_in[9];
  const float* bd  = (const float*)d_in[10];
  const float* Wo  = (const float*)d_in[11];
  const float* bo  = (const float*)d_in[12];

  const int n  = in_sizes[0] / 64;   // 50000 (< 65536 -> ssrc fits uint16)
  const int ne = in_sizes[2] / 2;    // 800000
  const int* srcI = eidx;
  const int* dstI = eidx + ne;

  // workspace carve-up (keep 4B alignment)
  int*   cnt    = (int*)d_ws;                     // n
  int*   rowptr = cnt + n;                        // n+1
  int*   bsum   = rowptr + n + 1;                 // 256
  int*   boff   = bsum + 256;                     // 256
  float* dinv   = (float*)(boff + 256);           // n
  __half* xwp   = (__half*)(dinv + n);            // n*64 halves
  float* h      = (float*)(xwp + (size_t)n * 64); // n*64 floats
  unsigned short* ssrc = (unsigned short*)(h + (size_t)n * 64); // ne (+pad)

  float* dout   = (float*)d_out;
  float* zbuf   = dout;                        // n*32
  float* outbuf = dout + (size_t)3 * n * 32;   // n*64

  const int BT = 256;
  auto blk = [](long long t) { return (int)((t + 255) / 256); };
  const int nb_n  = blk(n);
  const int nb_e  = blk(ne);
  const int nb_sc = (n + 1023) / 1024;
  const int nb_gw = blk((long long)n * 64);
  const int nb_g  = (n + 15) / 16;

  // ---- CSR setup ----
  hipLaunchKernelGGL(zero_i_kernel, dim3(nb_n), dim3(BT), 0, stream, cnt, n);
  hipLaunchKernelGGL(degree_i_kernel, dim3(nb_e), dim3(BT), 0, stream, dstI, cnt, ne);
  hipLaunchKernelGGL(scan1_kernel, dim3(nb_sc), dim3(BT), 0, stream, cnt, rowptr, bsum, n);
  hipLaunchKernelGGL(scanP_kernel, dim3(1), dim3(BT), 0, stream, bsum, boff, nb_sc, rowptr, n, ne);
  hipLaunchKernelGGL(scan2_kernel, dim3(nb_n), dim3(BT), 0, stream, rowptr, boff, cnt, dinv, n);
  hipLaunchKernelGGL(fill_kernel, dim3(nb_e), dim3(BT), 0, stream,
                     srcI, dstI, rowptr, cnt, ssrc, ne);

  // ---- encoder conv1: h = relu(gcn(concat(feat,cond), W1, b1)) ----
  hipLaunchKernelGGL((gemm_kernel<64, 32, 64, false, 16>), dim3(nb_g), dim3(BT), 0, stream,
                     feat, cond, W1, nullptr, dinv, xwp, n);
  hipLaunchKernelGGL((gather_kernel<0>), dim3(nb_gw), dim3(BT), 0, stream,
                     rowptr, ssrc, xwp, dinv, b1, nullptr, h, n);

  // ---- mean/logvar packed conv + reparam z ----
  hipLaunchKernelGGL((gemm_kernel<64, 0, 64, true, 16>), dim3(nb_g), dim3(BT), 0, stream,
                     h, nullptr, Wm, Wlv, dinv, xwp, n);
  hipLaunchKernelGGL((gather_kernel<1>), dim3(nb_gw), dim3(BT), 0, stream,
                     rowptr, ssrc, xwp, dinv, bm, blv, dout, n);

  // ---- decoder conv1: hd = relu(gcn(concat(z,cond), Wd, bd)) ----
  hipLaunchKernelGGL((gemm_kernel<32, 32, 64, false, 16>), dim3(nb_g), dim3(BT), 0, stream,
                     zbuf, cond, Wd, nullptr, dinv, xwp, n);
  hipLaunchKernelGGL((gather_kernel<0>), dim3(nb_gw), dim3(BT), 0, stream,
                     rowptr, ssrc, xwp, dinv, bd, nullptr, h, n);

  // ---- decoder out conv ----
  hipLaunchKernelGGL((gemm_kernel<64, 0, 64, false, 16>), dim3(nb_g), dim3(BT), 0, stream,
                     h, nullptr, Wo, nullptr, dinv, xwp, n);
  hipLaunchKernelGGL((gather_kernel<2>), dim3(nb_gw), dim3(BT), 0, stream,
                     rowptr, ssrc, xwp, dinv, bo, nullptr, outbuf, n);
}

// Round 5
// 302.710 us; speedup vs baseline: 3.0703x; 1.2410x over previous
//
#include <hip/hip_runtime.h>
#include <hip/hip_bf16.h>
#include <hip/hip_fp16.h>
#include <math.h>

// ---------------- JAX threefry2x32 (partitionable) + normal ----------------

static __device__ __forceinline__ unsigned rotl32(unsigned x, int d) {
  return (x << d) | (x >> (32 - d));
}

// key = (0, 42)  == jax.random.key(42)
static __device__ __forceinline__ void threefry_0_42(unsigned& x0, unsigned& x1) {
  const unsigned ks0 = 0u, ks1 = 42u, ks2 = 0u ^ 42u ^ 0x1BD11BDAu;
  x0 += ks0; x1 += ks1;
#define TF_R(r) { x0 += x1; x1 = rotl32(x1, (r)); x1 ^= x0; }
  TF_R(13) TF_R(15) TF_R(26) TF_R(6)
  x0 += ks1; x1 += ks2 + 1u;
  TF_R(17) TF_R(29) TF_R(16) TF_R(24)
  x0 += ks2; x1 += ks0 + 2u;
  TF_R(13) TF_R(15) TF_R(26) TF_R(6)
  x0 += ks0; x1 += ks1 + 3u;
  TF_R(17) TF_R(29) TF_R(16) TF_R(24)
  x0 += ks1; x1 += ks2 + 4u;
  TF_R(13) TF_R(15) TF_R(26) TF_R(6)
  x0 += ks2; x1 += ks0 + 5u;
#undef TF_R
}

static __device__ __forceinline__ float erfinv_f(float u) {
  float w = -logf((1.0f - u) * (1.0f + u));
  float p;
  if (w < 5.0f) {
    w = w - 2.5f;
    p = 2.81022636e-08f;
    p = fmaf(p, w, 3.43273939e-07f);
    p = fmaf(p, w, -3.5233877e-06f);
    p = fmaf(p, w, -4.39150654e-06f);
    p = fmaf(p, w, 0.00021858087f);
    p = fmaf(p, w, -0.00125372503f);
    p = fmaf(p, w, -0.00417768164f);
    p = fmaf(p, w, 0.246640727f);
    p = fmaf(p, w, 1.50140941f);
  } else {
    w = sqrtf(w) - 3.0f;
    p = -0.000200214257f;
    p = fmaf(p, w, 0.000100950558f);
    p = fmaf(p, w, 0.00134934322f);
    p = fmaf(p, w, -0.00367342844f);
    p = fmaf(p, w, 0.00573950773f);
    p = fmaf(p, w, -0.0076224613f);
    p = fmaf(p, w, 0.00943887047f);
    p = fmaf(p, w, 1.00167406f);
    p = fmaf(p, w, 2.83297682f);
  }
  return p * u;
}

// jax_threefry_partitionable=True: bits(j) = xor(threefry2x32(key, (0, j)))
static __device__ __forceinline__ float jax_normal_at(unsigned j) {
  unsigned x0 = 0u, x1 = j;
  threefry_0_42(x0, x1);
  unsigned bits = x0 ^ x1;
  float f = __uint_as_float((bits >> 9) | 0x3f800000u) - 1.0f;   // [0,1)
  float u = fmaf(f, 1.99999994f, -0.99999994f);
  return 1.41421356237f * erfinv_f(u);
}

// ---------------- setup kernels ----------------

__global__ void zero_i_kernel(int* __restrict__ p, int n) {
  int i = blockIdx.x * blockDim.x + threadIdx.x;
  if (i < n) p[i] = 0;
}

__global__ void degree_i_kernel(const int* __restrict__ dstI, int* __restrict__ cnt, int ne) {
  int e = blockIdx.x * blockDim.x + threadIdx.x;
  if (e < ne) atomicAdd(&cnt[dstI[e]], 1);
}

// ---- exclusive scan of cnt[n] -> rowptr ----
__global__ __launch_bounds__(256) void scan1_kernel(const int* __restrict__ cnt,
                                                    int* __restrict__ rowptr,
                                                    int* __restrict__ bsum, int n) {
  __shared__ int s[256];
  const int t = threadIdx.x;
  const int base = blockIdx.x * 1024 + t * 4;
  int v0 = (base + 0 < n) ? cnt[base + 0] : 0;
  int v1 = (base + 1 < n) ? cnt[base + 1] : 0;
  int v2 = (base + 2 < n) ? cnt[base + 2] : 0;
  int v3 = (base + 3 < n) ? cnt[base + 3] : 0;
  int tot = v0 + v1 + v2 + v3;
  s[t] = tot;
  __syncthreads();
  for (int off = 1; off < 256; off <<= 1) {
    int x = (t >= off) ? s[t - off] : 0;
    __syncthreads();
    s[t] += x;
    __syncthreads();
  }
  int excl = s[t] - tot;
  if (t == 255) bsum[blockIdx.x] = s[t];
  if (base + 0 < n) rowptr[base + 0] = excl;
  if (base + 1 < n) rowptr[base + 1] = excl + v0;
  if (base + 2 < n) rowptr[base + 2] = excl + v0 + v1;
  if (base + 3 < n) rowptr[base + 3] = excl + v0 + v1 + v2;
}

__global__ __launch_bounds__(256) void scanP_kernel(int* __restrict__ bsum,
                                                    int* __restrict__ boff,
                                                    int nb, int* __restrict__ rowptr,
                                                    int n, int ne) {
  __shared__ int s[256];
  const int t = threadIdx.x;
  int v = (t < nb) ? bsum[t] : 0;
  s[t] = v;
  __syncthreads();
  for (int off = 1; off < 256; off <<= 1) {
    int x = (t >= off) ? s[t - off] : 0;
    __syncthreads();
    s[t] += x;
    __syncthreads();
  }
  if (t < nb) boff[t] = s[t] - v;
  if (t == 0) rowptr[n] = ne;
}

// adds block offsets; computes dinv; zeroes cnt for reuse as fill cursor
__global__ void scan2_kernel(int* __restrict__ rowptr, const int* __restrict__ boff,
                             int* __restrict__ cnt, float* __restrict__ dinv, int n) {
  int i = blockIdx.x * blockDim.x + threadIdx.x;
  if (i < n) {
    rowptr[i] += boff[i >> 10];
    float d = (float)cnt[i] + 1.0f;
    dinv[i] = 1.0f / sqrtf(d);
    cnt[i] = 0;
  }
}

// counting-sort fill: dst-sorted src indices (uint16, n < 65536)
__global__ void fill_kernel(const int* __restrict__ srcI, const int* __restrict__ dstI,
                            const int* __restrict__ rowptr, int* __restrict__ cnt,
                            unsigned short* __restrict__ ssrc, int ne) {
  int e = blockIdx.x * blockDim.x + threadIdx.x;
  if (e >= ne) return;
  int s = srcI[e], d = dstI[e];
  int pos = rowptr[d] + atomicAdd(&cnt[d], 1);
  ssrc[pos] = (unsigned short)s;
}

// ---------------- tiled GEMM: Y[n][64] = concat(X1,X2)@W * dinv, fp16 out ----------------
// 64 nodes/block, 256 threads, thread tile = 4 nodes x 4 cols.
struct alignas(8) half4 { __half a, b, c, d; };

template<int IN1, int IN2, bool DUALW>
__global__ __launch_bounds__(256) void gemm_kernel(
    const float* __restrict__ X1, const float* __restrict__ X2,
    const float* __restrict__ Wa, const float* __restrict__ Wb,
    const float* __restrict__ dinv, __half* __restrict__ Y, int n) {
  constexpr int IN = IN1 + IN2;
  constexpr int IP = IN + 4;       // padded stride, keeps 16B alignment, 2-way banks only
  __shared__ float xs[64 * IP];
  __shared__ float ws[IN * 64];

  const int tid = threadIdx.x;
  const int base = blockIdx.x * 64;

  // stage W
  for (int i = tid; i < IN * 64; i += 256) {
    if (DUALW) {
      int k = i >> 6, c = i & 63;
      ws[i] = (c < 32) ? Wa[k * 32 + c] : Wb[k * 32 + (c - 32)];
    } else {
      ws[i] = Wa[i];
    }
  }
  // stage X1 (float4 coalesced)
  for (int idx = tid; idx < 64 * (IN1 / 4); idx += 256) {
    int node = idx / (IN1 / 4);
    int k4 = (idx % (IN1 / 4)) * 4;
    int g = base + node;
    float4 v = (g < n) ? *(const float4*)(X1 + (size_t)g * IN1 + k4)
                       : make_float4(0.f, 0.f, 0.f, 0.f);
    *(float4*)&xs[node * IP + k4] = v;
  }
  // stage X2
  if (IN2 > 0) {
    for (int idx = tid; idx < 64 * (IN2 / 4); idx += 256) {
      int node = idx / (IN2 / 4);
      int k4 = (idx % (IN2 / 4)) * 4;
      int g = base + node;
      float4 v = (g < n) ? *(const float4*)(X2 + (size_t)g * IN2 + k4)
                         : make_float4(0.f, 0.f, 0.f, 0.f);
      *(float4*)&xs[node * IP + IN1 + k4] = v;
    }
  }
  __syncthreads();

  const int tc = (tid & 15) * 4;        // col
  const int tr = (tid >> 4) * 4;        // node in tile
  float acc[4][4];
#pragma unroll
  for (int i = 0; i < 4; ++i)
#pragma unroll
    for (int c = 0; c < 4; ++c) acc[i][c] = 0.0f;

#pragma unroll 4
  for (int kk = 0; kk < IN; kk += 4) {
    float4 xv[4], wv[4];
#pragma unroll
    for (int i = 0; i < 4; ++i) xv[i] = *(const float4*)&xs[(tr + i) * IP + kk];
#pragma unroll
    for (int j = 0; j < 4; ++j) wv[j] = *(const float4*)&ws[(kk + j) * 64 + tc];
#pragma unroll
    for (int i = 0; i < 4; ++i) {
#pragma unroll
      for (int c = 0; c < 4; ++c) {
        float* w0 = (float*)&wv[0];
        float* x0 = (float*)&xv[i];
        acc[i][c] = fmaf(x0[0], ((float*)&wv[0])[c], acc[i][c]);
        acc[i][c] = fmaf(x0[1], ((float*)&wv[1])[c], acc[i][c]);
        acc[i][c] = fmaf(x0[2], ((float*)&wv[2])[c], acc[i][c]);
        acc[i][c] = fmaf(x0[3], ((float*)&wv[3])[c], acc[i][c]);
        (void)w0;
      }
    }
  }

#pragma unroll
  for (int i = 0; i < 4; ++i) {
    int g = base + tr + i;
    if (g < n) {
      float dv = dinv[g];
      half4 o;
      o.a = __float2half(acc[i][0] * dv);
      o.b = __float2half(acc[i][1] * dv);
      o.c = __float2half(acc[i][2] * dv);
      o.d = __float2half(acc[i][3] * dv);
      *(half4*)&Y[(size_t)g * 64 + tc] = o;
    }
  }
}

// ---------------- CSR gather + fused finalize ----------------
// one wave per node; lane = column. agg = dinv[d]*(sum_edges xwp[s] + xwp[d])
// MODE 0: +bias, relu -> out. MODE 1: mean||logvar packed -> z/mean/logvar. MODE 2: +bias -> out
template<int MODE>
__global__ __launch_bounds__(256) void gather_kernel(
    const int* __restrict__ rowptr, const unsigned short* __restrict__ ssrc,
    const __half* __restrict__ xwp, const float* __restrict__ dinv,
    const float* __restrict__ b0, const float* __restrict__ b1,
    float* __restrict__ out, int n) {
  const int node = (blockIdx.x * 256 + threadIdx.x) >> 6;
  const int lane = threadIdx.x & 63;
  if (node >= n) return;
  const int beg = rowptr[node];
  const int end = rowptr[node + 1];
  float acc = __half2float(xwp[(size_t)node * 64 + lane]);  // self loop
  float acc2 = 0.0f;
  for (int cbase = beg; cbase < end; cbase += 64) {
    int m = end - cbase; if (m > 64) m = 64;
    unsigned sv = (lane < m) ? (unsigned)ssrc[cbase + lane] : 0u;
    int k = 0;
    for (; k + 1 < m; k += 2) {
      unsigned s0 = __shfl(sv, k, 64);
      unsigned s1 = __shfl(sv, k + 1, 64);
      acc  += __half2float(xwp[(size_t)s0 * 64 + lane]);
      acc2 += __half2float(xwp[(size_t)s1 * 64 + lane]);
    }
    if (k < m) {
      unsigned s0 = __shfl(sv, k, 64);
      acc += __half2float(xwp[(size_t)s0 * 64 + lane]);
    }
  }
  acc = (acc + acc2) * dinv[node];

  if (MODE == 0) {
    out[(size_t)node * 64 + lane] = fmaxf(acc + b0[lane], 0.0f);
  } else if (MODE == 2) {
    out[(size_t)node * 64 + lane] = acc + b0[lane];
  } else {
    // MODE 1: lanes 0..31 = mean cols, 32..63 = logvar cols
    float v = acc + ((lane < 32) ? b0[lane] : b1[lane - 32]);
    float other = __shfl(v, lane ^ 32, 64);
    const int NZ = n * 32;
    if (lane < 32) {
      int j = node * 32 + lane;
      float noise = jax_normal_at((unsigned)j);
      out[j] = fmaf(noise, expf(0.5f * other), v);  // z
      out[NZ + j] = v;                              // mean
    } else {
      out[2 * NZ + node * 32 + (lane - 32)] = v;    // logvar
    }
  }
}

// ---------------- launch ----------------

extern "C" void kernel_launch(void* const* d_in, const int* in_sizes, int n_in,
                              void* d_out, int out_size, void* d_ws, size_t ws_size,
                              hipStream_t stream) {
  const float* feat = (const float*)d_in[0];
  const float* cond = (const float*)d_in[1];
  const int*   eidx = (const int*)d_in[2];
  const float* W1  = (const float*)d_in[3];
  const float* b1  = (const float*)d_in[4];
  const float* Wm  = (const float*)d_in[5];
  const float* bm  = (const float*)d_in[6];
  const float* Wlv = (const float*)d_in[7];
  const float* blv = (const float*)d_in[8];
  const float* Wd  = (const float*)d_in[9];
  const float* bd  = (const float*)d_in[10];
  const float* Wo  = (const float*)d_in[11];
  const float* bo  = (const float*)d_in[12];

  const int n  = in_sizes[0] / 64;   // 50000 (< 65536 -> ssrc fits uint16)
  const int ne = in_sizes[2] / 2;    // 800000
  const int* srcI = eidx;
  const int* dstI = eidx + ne;

  // workspace carve-up (keep 4B alignment)
  int*   cnt    = (int*)d_ws;                     // n
  int*   rowptr = cnt + n;                        // n+1
  int*   bsum   = rowptr + n + 1;                 // 256
  int*   boff   = bsum + 256;                     // 256
  float* dinv   = (float*)(boff + 256);           // n
  __half* xwp   = (__half*)(dinv + n);            // n*64 halves
  float* h      = (float*)(xwp + (size_t)n * 64); // n*64 floats
  unsigned short* ssrc = (unsigned short*)(h + (size_t)n * 64); // ne (+pad)

  float* dout   = (float*)d_out;
  float* zbuf   = dout;                        // n*32
  float* outbuf = dout + (size_t)3 * n * 32;   // n*64

  const int BT = 256;
  auto blk = [](long long t) { return (int)((t + 255) / 256); };
  const int nb_n  = blk(n);
  const int nb_e  = blk(ne);
  const int nb_sc = (n + 1023) / 1024;
  const int nb_gw = blk((long long)n * 64);
  const int nb_g  = (n + 63) / 64;

  // ---- CSR setup ----
  hipLaunchKernelGGL(zero_i_kernel, dim3(nb_n), dim3(BT), 0, stream, cnt, n);
  hipLaunchKernelGGL(degree_i_kernel, dim3(nb_e), dim3(BT), 0, stream, dstI, cnt, ne);
  hipLaunchKernelGGL(scan1_kernel, dim3(nb_sc), dim3(BT), 0, stream, cnt, rowptr, bsum, n);
  hipLaunchKernelGGL(scanP_kernel, dim3(1), dim3(BT), 0, stream, bsum, boff, nb_sc, rowptr, n, ne);
  hipLaunchKernelGGL(scan2_kernel, dim3(nb_n), dim3(BT), 0, stream, rowptr, boff, cnt, dinv, n);
  hipLaunchKernelGGL(fill_kernel, dim3(nb_e), dim3(BT), 0, stream,
                     srcI, dstI, rowptr, cnt, ssrc, ne);

  // ---- encoder conv1: h = relu(gcn(concat(feat,cond), W1, b1)) ----
  hipLaunchKernelGGL((gemm_kernel<64, 32, false>), dim3(nb_g), dim3(BT), 0, stream,
                     feat, cond, W1, nullptr, dinv, xwp, n);
  hipLaunchKernelGGL((gather_kernel<0>), dim3(nb_gw), dim3(BT), 0, stream,
                     rowptr, ssrc, xwp, dinv, b1, nullptr, h, n);

  // ---- mean/logvar packed conv + reparam z ----
  hipLaunchKernelGGL((gemm_kernel<64, 0, true>), dim3(nb_g), dim3(BT), 0, stream,
                     h, nullptr, Wm, Wlv, dinv, xwp, n);
  hipLaunchKernelGGL((gather_kernel<1>), dim3(nb_gw), dim3(BT), 0, stream,
                     rowptr, ssrc, xwp, dinv, bm, blv, dout, n);

  // ---- decoder conv1: hd = relu(gcn(concat(z,cond), Wd, bd)) ----
  hipLaunchKernelGGL((gemm_kernel<32, 32, false>), dim3(nb_g), dim3(BT), 0, stream,
                     zbuf, cond, Wd, nullptr, dinv, xwp, n);
  hipLaunchKernelGGL((gather_kernel<0>), dim3(nb_gw), dim3(BT), 0, stream,
                     rowptr, ssrc, xwp, dinv, bd, nullptr, h, n);

  // ---- decoder out conv ----
  hipLaunchKernelGGL((gemm_kernel<64, 0, false>), dim3(nb_g), dim3(BT), 0, stream,
                     h, nullptr, Wo, nullptr, dinv, xwp, n);
  hipLaunchKernelGGL((gather_kernel<2>), dim3(nb_gw), dim3(BT), 0, stream,
                     rowptr, ssrc, xwp, dinv, bo, nullptr, outbuf, n);
}

// Round 6
// 279.638 us; speedup vs baseline: 3.3236x; 1.0825x over previous
//
#include <hip/hip_runtime.h>
#include <hip/hip_bf16.h>
#include <hip/hip_fp16.h>
#include <math.h>

// ---------------- JAX threefry2x32 (partitionable) + normal ----------------

static __device__ __forceinline__ unsigned rotl32(unsigned x, int d) {
  return (x << d) | (x >> (32 - d));
}

// key = (0, 42)  == jax.random.key(42)
static __device__ __forceinline__ void threefry_0_42(unsigned& x0, unsigned& x1) {
  const unsigned ks0 = 0u, ks1 = 42u, ks2 = 0u ^ 42u ^ 0x1BD11BDAu;
  x0 += ks0; x1 += ks1;
#define TF_R(r) { x0 += x1; x1 = rotl32(x1, (r)); x1 ^= x0; }
  TF_R(13) TF_R(15) TF_R(26) TF_R(6)
  x0 += ks1; x1 += ks2 + 1u;
  TF_R(17) TF_R(29) TF_R(16) TF_R(24)
  x0 += ks2; x1 += ks0 + 2u;
  TF_R(13) TF_R(15) TF_R(26) TF_R(6)
  x0 += ks0; x1 += ks1 + 3u;
  TF_R(17) TF_R(29) TF_R(16) TF_R(24)
  x0 += ks1; x1 += ks2 + 4u;
  TF_R(13) TF_R(15) TF_R(26) TF_R(6)
  x0 += ks2; x1 += ks0 + 5u;
#undef TF_R
}

static __device__ __forceinline__ float erfinv_f(float u) {
  float w = -logf((1.0f - u) * (1.0f + u));
  float p;
  if (w < 5.0f) {
    w = w - 2.5f;
    p = 2.81022636e-08f;
    p = fmaf(p, w, 3.43273939e-07f);
    p = fmaf(p, w, -3.5233877e-06f);
    p = fmaf(p, w, -4.39150654e-06f);
    p = fmaf(p, w, 0.00021858087f);
    p = fmaf(p, w, -0.00125372503f);
    p = fmaf(p, w, -0.00417768164f);
    p = fmaf(p, w, 0.246640727f);
    p = fmaf(p, w, 1.50140941f);
  } else {
    w = sqrtf(w) - 3.0f;
    p = -0.000200214257f;
    p = fmaf(p, w, 0.000100950558f);
    p = fmaf(p, w, 0.00134934322f);
    p = fmaf(p, w, -0.00367342844f);
    p = fmaf(p, w, 0.00573950773f);
    p = fmaf(p, w, -0.0076224613f);
    p = fmaf(p, w, 0.00943887047f);
    p = fmaf(p, w, 1.00167406f);
    p = fmaf(p, w, 2.83297682f);
  }
  return p * u;
}

// jax_threefry_partitionable=True: bits(j) = xor(threefry2x32(key, (0, j)))
static __device__ __forceinline__ float jax_normal_at(unsigned j) {
  unsigned x0 = 0u, x1 = j;
  threefry_0_42(x0, x1);
  unsigned bits = x0 ^ x1;
  float f = __uint_as_float((bits >> 9) | 0x3f800000u) - 1.0f;   // [0,1)
  float u = fmaf(f, 1.99999994f, -0.99999994f);
  return 1.41421356237f * erfinv_f(u);
}

// ---------------- setup kernels ----------------

__global__ void zero_i_kernel(int* __restrict__ p, int n) {
  int i = blockIdx.x * blockDim.x + threadIdx.x;
  if (i < n) p[i] = 0;
}

__global__ void degree_i_kernel(const int* __restrict__ dstI, int* __restrict__ cnt, int ne) {
  int e = blockIdx.x * blockDim.x + threadIdx.x;
  if (e < ne) atomicAdd(&cnt[dstI[e]], 1);
}

// ---- exclusive scan of cnt[n] -> rowptr ----
__global__ __launch_bounds__(256) void scan1_kernel(const int* __restrict__ cnt,
                                                    int* __restrict__ rowptr,
                                                    int* __restrict__ bsum, int n) {
  __shared__ int s[256];
  const int t = threadIdx.x;
  const int base = blockIdx.x * 1024 + t * 4;
  int v0 = (base + 0 < n) ? cnt[base + 0] : 0;
  int v1 = (base + 1 < n) ? cnt[base + 1] : 0;
  int v2 = (base + 2 < n) ? cnt[base + 2] : 0;
  int v3 = (base + 3 < n) ? cnt[base + 3] : 0;
  int tot = v0 + v1 + v2 + v3;
  s[t] = tot;
  __syncthreads();
  for (int off = 1; off < 256; off <<= 1) {
    int x = (t >= off) ? s[t - off] : 0;
    __syncthreads();
    s[t] += x;
    __syncthreads();
  }
  int excl = s[t] - tot;
  if (t == 255) bsum[blockIdx.x] = s[t];
  if (base + 0 < n) rowptr[base + 0] = excl;
  if (base + 1 < n) rowptr[base + 1] = excl + v0;
  if (base + 2 < n) rowptr[base + 2] = excl + v0 + v1;
  if (base + 3 < n) rowptr[base + 3] = excl + v0 + v1 + v2;
}

__global__ __launch_bounds__(256) void scanP_kernel(int* __restrict__ bsum,
                                                    int* __restrict__ boff,
                                                    int nb, int* __restrict__ rowptr,
                                                    int n, int ne) {
  __shared__ int s[256];
  const int t = threadIdx.x;
  int v = (t < nb) ? bsum[t] : 0;
  s[t] = v;
  __syncthreads();
  for (int off = 1; off < 256; off <<= 1) {
    int x = (t >= off) ? s[t - off] : 0;
    __syncthreads();
    s[t] += x;
    __syncthreads();
  }
  if (t < nb) boff[t] = s[t] - v;
  if (t == 0) rowptr[n] = ne;
}

// adds block offsets; computes dinv; zeroes cnt for reuse as fill cursor
__global__ void scan2_kernel(int* __restrict__ rowptr, const int* __restrict__ boff,
                             int* __restrict__ cnt, float* __restrict__ dinv, int n) {
  int i = blockIdx.x * blockDim.x + threadIdx.x;
  if (i < n) {
    rowptr[i] += boff[i >> 10];
    float d = (float)cnt[i] + 1.0f;
    dinv[i] = 1.0f / sqrtf(d);
    cnt[i] = 0;
  }
}

// counting-sort fill: dst-sorted src indices (uint16, n < 65536)
__global__ void fill_kernel(const int* __restrict__ srcI, const int* __restrict__ dstI,
                            const int* __restrict__ rowptr, int* __restrict__ cnt,
                            unsigned short* __restrict__ ssrc, int ne) {
  int e = blockIdx.x * blockDim.x + threadIdx.x;
  if (e >= ne) return;
  int s = srcI[e], d = dstI[e];
  int pos = rowptr[d] + atomicAdd(&cnt[d], 1);
  ssrc[pos] = (unsigned short)s;
}

// ---------------- tiled GEMM: Y[n][64] = concat(X1,X2)@W * dinv, fp16 out ----------------
// 128 nodes/block, 256 threads, thread tile = 4 nodes x 8 cols.
struct alignas(16) half8 { __half h[8]; };

template<int IN1, int IN2, bool DUALW>
__global__ __launch_bounds__(256) void gemm_kernel(
    const float* __restrict__ X1, const float* __restrict__ X2,
    const float* __restrict__ Wa, const float* __restrict__ Wb,
    const float* __restrict__ dinv, __half* __restrict__ Y, int n) {
  constexpr int IN = IN1 + IN2;
  constexpr int IP = IN + 4;       // padded stride (16B-aligned rows, 2-way banks only)
  __shared__ float xs[128 * IP];
  __shared__ float ws[IN * 64];

  const int tid = threadIdx.x;
  const int base = blockIdx.x * 128;

  // stage W
  for (int i = tid; i < IN * 64; i += 256) {
    if (DUALW) {
      int k = i >> 6, c = i & 63;
      ws[i] = (c < 32) ? Wa[k * 32 + c] : Wb[k * 32 + (c - 32)];
    } else {
      ws[i] = Wa[i];
    }
  }
  // stage X1 (float4 coalesced)
  for (int idx = tid; idx < 128 * (IN1 / 4); idx += 256) {
    int node = idx / (IN1 / 4);
    int k4 = (idx % (IN1 / 4)) * 4;
    int g = base + node;
    float4 v = (g < n) ? *(const float4*)(X1 + (size_t)g * IN1 + k4)
                       : make_float4(0.f, 0.f, 0.f, 0.f);
    *(float4*)&xs[node * IP + k4] = v;
  }
  // stage X2
  if (IN2 > 0) {
    for (int idx = tid; idx < 128 * (IN2 / 4); idx += 256) {
      int node = idx / (IN2 / 4);
      int k4 = (idx % (IN2 / 4)) * 4;
      int g = base + node;
      float4 v = (g < n) ? *(const float4*)(X2 + (size_t)g * IN2 + k4)
                         : make_float4(0.f, 0.f, 0.f, 0.f);
      *(float4*)&xs[node * IP + IN1 + k4] = v;
    }
  }
  __syncthreads();

  const int c8 = (tid & 7) * 8;         // col base (8 cols)
  const int r4 = (tid >> 3) * 4;        // node base (4 nodes)
  float acc[4][8];
#pragma unroll
  for (int i = 0; i < 4; ++i)
#pragma unroll
    for (int c = 0; c < 8; ++c) acc[i][c] = 0.0f;

#pragma unroll 2
  for (int kk = 0; kk < IN; kk += 4) {
    float4 xv[4];
    float4 wv[4][2];
#pragma unroll
    for (int i = 0; i < 4; ++i) xv[i] = *(const float4*)&xs[(r4 + i) * IP + kk];
#pragma unroll
    for (int j = 0; j < 4; ++j) {
      wv[j][0] = *(const float4*)&ws[(kk + j) * 64 + c8];
      wv[j][1] = *(const float4*)&ws[(kk + j) * 64 + c8 + 4];
    }
#pragma unroll
    for (int i = 0; i < 4; ++i) {
      const float* xi = (const float*)&xv[i];
#pragma unroll
      for (int j = 0; j < 4; ++j) {
        const float* wj = (const float*)&wv[j][0];
#pragma unroll
        for (int c = 0; c < 8; ++c) {
          acc[i][c] = fmaf(xi[j], wj[c], acc[i][c]);
        }
      }
    }
  }

#pragma unroll
  for (int i = 0; i < 4; ++i) {
    int g = base + r4 + i;
    if (g < n) {
      float dv = dinv[g];
      half8 o;
#pragma unroll
      for (int c = 0; c < 8; ++c) o.h[c] = __float2half(acc[i][c] * dv);
      *(half8*)&Y[(size_t)g * 64 + c8] = o;
    }
  }
}

// ---------------- CSR gather + fused finalize (half2 lanes) ----------------
// one wave per node. lane = half*32 + cl; cl covers cols (2cl, 2cl+1).
// half 0 accumulates even edges (+self), half 1 odd edges; combined via shfl^32.
// MODE 0: +bias, relu -> out. MODE 1: mean||logvar packed -> z/mean/logvar. MODE 2: +bias -> out
template<int MODE>
__global__ __launch_bounds__(256) void gather_kernel(
    const int* __restrict__ rowptr, const unsigned short* __restrict__ ssrc,
    const __half* __restrict__ xwp, const float* __restrict__ dinv,
    const float* __restrict__ b0, const float* __restrict__ b1,
    float* __restrict__ out, int n) {
  const int node = (blockIdx.x * 256 + threadIdx.x) >> 6;
  const int lane = threadIdx.x & 63;
  if (node >= n) return;
  const int hf = lane >> 5;       // edge parity handled by this lane
  const int cl = lane & 31;       // column pair index

  float2 acc, acc2;
  acc2.x = 0.f; acc2.y = 0.f;
  {
    float2 f = __half22float2(((const __half2*)(xwp + (size_t)node * 64))[cl]);
    acc.x = hf ? 0.f : f.x;
    acc.y = hf ? 0.f : f.y;
  }

  const int beg = rowptr[node];
  const int end = rowptr[node + 1];
  for (int cbase = beg; cbase < end; cbase += 64) {
    int m = end - cbase; if (m > 64) m = 64;
    unsigned sv = (lane < m) ? (unsigned)ssrc[cbase + lane] : 0u;
    int k = 0;
    for (; k + 3 < m; k += 4) {
      unsigned sa = __shfl(sv, k + hf, 64);
      unsigned sb = __shfl(sv, k + 2 + hf, 64);
      float2 fa = __half22float2(((const __half2*)(xwp + (size_t)sa * 64))[cl]);
      float2 fb = __half22float2(((const __half2*)(xwp + (size_t)sb * 64))[cl]);
      acc.x += fa.x;  acc.y += fa.y;
      acc2.x += fb.x; acc2.y += fb.y;
    }
    if (k + 1 < m) {
      unsigned sa = __shfl(sv, k + hf, 64);
      float2 fa = __half22float2(((const __half2*)(xwp + (size_t)sa * 64))[cl]);
      acc.x += fa.x; acc.y += fa.y;
      k += 2;
    }
    if (k < m) {  // single tail edge -> half 0 only
      unsigned sa = __shfl(sv, k, 64);
      if (hf == 0) {
        float2 fa = __half22float2(((const __half2*)(xwp + (size_t)sa * 64))[cl]);
        acc.x += fa.x; acc.y += fa.y;
      }
    }
  }
  acc.x += acc2.x; acc.y += acc2.y;
  // combine lane halves (lane ^ 32 holds the other parity's partial)
  acc.x += __shfl(acc.x, lane ^ 32, 64);
  acc.y += __shfl(acc.y, lane ^ 32, 64);
  float dv = dinv[node];
  float vx = acc.x * dv, vy = acc.y * dv;

  if (hf != 0) return;  // lanes 0..31 write

  const int c0 = 2 * cl;
  if (MODE == 0) {
    float2 o;
    o.x = fmaxf(vx + b0[c0], 0.0f);
    o.y = fmaxf(vy + b0[c0 + 1], 0.0f);
    ((float2*)(out + (size_t)node * 64))[cl] = o;
  } else if (MODE == 2) {
    float2 o;
    o.x = vx + b0[c0];
    o.y = vy + b0[c0 + 1];
    ((float2*)(out + (size_t)node * 64))[cl] = o;
  } else {
    // MODE 1: cols 0..31 mean (cl<16), cols 32..63 logvar (cl>=16)
    float bx = (c0 < 32) ? b0[c0] : b1[c0 - 32];
    float by = (c0 + 1 < 32) ? b0[c0 + 1] : b1[c0 + 1 - 32];
    vx += bx; vy += by;
    // partner: lane cl+16 holds cols (c0+32, c0+33)
    float ox = __shfl(vx, lane + 16, 64);
    float oy = __shfl(vy, lane + 16, 64);
    const int NZ = n * 32;
    if (cl < 16) {
      int j = node * 32 + c0;
      float n0 = jax_normal_at((unsigned)j);
      float n1 = jax_normal_at((unsigned)(j + 1));
      out[j]     = fmaf(n0, expf(0.5f * ox), vx);  // z
      out[j + 1] = fmaf(n1, expf(0.5f * oy), vy);
      out[NZ + j]     = vx;                        // mean
      out[NZ + j + 1] = vy;
    } else {
      int j = node * 32 + (c0 - 32);
      out[2 * NZ + j]     = vx;                    // logvar
      out[2 * NZ + j + 1] = vy;
    }
  }
}

// ---------------- launch ----------------

extern "C" void kernel_launch(void* const* d_in, const int* in_sizes, int n_in,
                              void* d_out, int out_size, void* d_ws, size_t ws_size,
                              hipStream_t stream) {
  const float* feat = (const float*)d_in[0];
  const float* cond = (const float*)d_in[1];
  const int*   eidx = (const int*)d_in[2];
  const float* W1  = (const float*)d_in[3];
  const float* b1  = (const float*)d_in[4];
  const float* Wm  = (const float*)d_in[5];
  const float* bm  = (const float*)d_in[6];
  const float* Wlv = (const float*)d_in[7];
  const float* blv = (const float*)d_in[8];
  const float* Wd  = (const float*)d_in[9];
  const float* bd  = (const float*)d_in[10];
  const float* Wo  = (const float*)d_in[11];
  const float* bo  = (const float*)d_in[12];

  const int n  = in_sizes[0] / 64;   // 50000 (< 65536 -> ssrc fits uint16)
  const int ne = in_sizes[2] / 2;    // 800000
  const int* srcI = eidx;
  const int* dstI = eidx + ne;

  // workspace carve-up (keep 4B alignment)
  int*   cnt    = (int*)d_ws;                     // n
  int*   rowptr = cnt + n;                        // n+1
  int*   bsum   = rowptr + n + 1;                 // 256
  int*   boff   = bsum + 256;                     // 256
  float* dinv   = (float*)(boff + 256);           // n
  __half* xwp   = (__half*)(dinv + n);            // n*64 halves
  float* h      = (float*)(xwp + (size_t)n * 64); // n*64 floats
  unsigned short* ssrc = (unsigned short*)(h + (size_t)n * 64); // ne

  float* dout   = (float*)d_out;
  float* zbuf   = dout;                        // n*32
  float* outbuf = dout + (size_t)3 * n * 32;   // n*64

  const int BT = 256;
  auto blk = [](long long t) { return (int)((t + 255) / 256); };
  const int nb_n  = blk(n);
  const int nb_e  = blk(ne);
  const int nb_sc = (n + 1023) / 1024;
  const int nb_gw = blk((long long)n * 64);
  const int nb_g  = (n + 127) / 128;

  // ---- CSR setup ----
  hipLaunchKernelGGL(zero_i_kernel, dim3(nb_n), dim3(BT), 0, stream, cnt, n);
  hipLaunchKernelGGL(degree_i_kernel, dim3(nb_e), dim3(BT), 0, stream, dstI, cnt, ne);
  hipLaunchKernelGGL(scan1_kernel, dim3(nb_sc), dim3(BT), 0, stream, cnt, rowptr, bsum, n);
  hipLaunchKernelGGL(scanP_kernel, dim3(1), dim3(BT), 0, stream, bsum, boff, nb_sc, rowptr, n, ne);
  hipLaunchKernelGGL(scan2_kernel, dim3(nb_n), dim3(BT), 0, stream, rowptr, boff, cnt, dinv, n);
  hipLaunchKernelGGL(fill_kernel, dim3(nb_e), dim3(BT), 0, stream,
                     srcI, dstI, rowptr, cnt, ssrc, ne);

  // ---- encoder conv1: h = relu(gcn(concat(feat,cond), W1, b1)) ----
  hipLaunchKernelGGL((gemm_kernel<64, 32, false>), dim3(nb_g), dim3(BT), 0, stream,
                     feat, cond, W1, nullptr, dinv, xwp, n);
  hipLaunchKernelGGL((gather_kernel<0>), dim3(nb_gw), dim3(BT), 0, stream,
                     rowptr, ssrc, xwp, dinv, b1, nullptr, h, n);

  // ---- mean/logvar packed conv + reparam z ----
  hipLaunchKernelGGL((gemm_kernel<64, 0, true>), dim3(nb_g), dim3(BT), 0, stream,
                     h, nullptr, Wm, Wlv, dinv, xwp, n);
  hipLaunchKernelGGL((gather_kernel<1>), dim3(nb_gw), dim3(BT), 0, stream,
                     rowptr, ssrc, xwp, dinv, bm, blv, dout, n);

  // ---- decoder conv1: hd = relu(gcn(concat(z,cond), Wd, bd)) ----
  hipLaunchKernelGGL((gemm_kernel<32, 32, false>), dim3(nb_g), dim3(BT), 0, stream,
                     zbuf, cond, Wd, nullptr, dinv, xwp, n);
  hipLaunchKernelGGL((gather_kernel<0>), dim3(nb_gw), dim3(BT), 0, stream,
                     rowptr, ssrc, xwp, dinv, bd, nullptr, h, n);

  // ---- decoder out conv ----
  hipLaunchKernelGGL((gemm_kernel<64, 0, false>), dim3(nb_g), dim3(BT), 0, stream,
                     h, nullptr, Wo, nullptr, dinv, xwp, n);
  hipLaunchKernelGGL((gather_kernel<2>), dim3(nb_gw), dim3(BT), 0, stream,
                     rowptr, ssrc, xwp, dinv, bo, nullptr, outbuf, n);
}

// Round 7
// 273.313 us; speedup vs baseline: 3.4005x; 1.0231x over previous
//
#include <hip/hip_runtime.h>
#include <hip/hip_bf16.h>
#include <hip/hip_fp16.h>
#include <math.h>

// ---------------- JAX threefry2x32 (partitionable) + normal ----------------

static __device__ __forceinline__ unsigned rotl32(unsigned x, int d) {
  return (x << d) | (x >> (32 - d));
}

// key = (0, 42)  == jax.random.key(42)
static __device__ __forceinline__ void threefry_0_42(unsigned& x0, unsigned& x1) {
  const unsigned ks0 = 0u, ks1 = 42u, ks2 = 0u ^ 42u ^ 0x1BD11BDAu;
  x0 += ks0; x1 += ks1;
#define TF_R(r) { x0 += x1; x1 = rotl32(x1, (r)); x1 ^= x0; }
  TF_R(13) TF_R(15) TF_R(26) TF_R(6)
  x0 += ks1; x1 += ks2 + 1u;
  TF_R(17) TF_R(29) TF_R(16) TF_R(24)
  x0 += ks2; x1 += ks0 + 2u;
  TF_R(13) TF_R(15) TF_R(26) TF_R(6)
  x0 += ks0; x1 += ks1 + 3u;
  TF_R(17) TF_R(29) TF_R(16) TF_R(24)
  x0 += ks1; x1 += ks2 + 4u;
  TF_R(13) TF_R(15) TF_R(26) TF_R(6)
  x0 += ks2; x1 += ks0 + 5u;
#undef TF_R
}

static __device__ __forceinline__ float erfinv_f(float u) {
  float w = -logf((1.0f - u) * (1.0f + u));
  float p;
  if (w < 5.0f) {
    w = w - 2.5f;
    p = 2.81022636e-08f;
    p = fmaf(p, w, 3.43273939e-07f);
    p = fmaf(p, w, -3.5233877e-06f);
    p = fmaf(p, w, -4.39150654e-06f);
    p = fmaf(p, w, 0.00021858087f);
    p = fmaf(p, w, -0.00125372503f);
    p = fmaf(p, w, -0.00417768164f);
    p = fmaf(p, w, 0.246640727f);
    p = fmaf(p, w, 1.50140941f);
  } else {
    w = sqrtf(w) - 3.0f;
    p = -0.000200214257f;
    p = fmaf(p, w, 0.000100950558f);
    p = fmaf(p, w, 0.00134934322f);
    p = fmaf(p, w, -0.00367342844f);
    p = fmaf(p, w, 0.00573950773f);
    p = fmaf(p, w, -0.0076224613f);
    p = fmaf(p, w, 0.00943887047f);
    p = fmaf(p, w, 1.00167406f);
    p = fmaf(p, w, 2.83297682f);
  }
  return p * u;
}

// jax_threefry_partitionable=True: bits(j) = xor(threefry2x32(key, (0, j)))
static __device__ __forceinline__ float jax_normal_at(unsigned j) {
  unsigned x0 = 0u, x1 = j;
  threefry_0_42(x0, x1);
  unsigned bits = x0 ^ x1;
  float f = __uint_as_float((bits >> 9) | 0x3f800000u) - 1.0f;   // [0,1)
  float u = fmaf(f, 1.99999994f, -0.99999994f);
  return 1.41421356237f * erfinv_f(u);
}

// ---------------- setup kernels ----------------

__global__ void zero_i_kernel(int* __restrict__ p, int n) {
  int i = blockIdx.x * blockDim.x + threadIdx.x;
  if (i < n) p[i] = 0;
}

__global__ void degree_i_kernel(const int* __restrict__ dstI, int* __restrict__ cnt, int ne) {
  int e = blockIdx.x * blockDim.x + threadIdx.x;
  if (e < ne) atomicAdd(&cnt[dstI[e]], 1);
}

// ---- exclusive scan of cnt[n] -> rowptr ----
__global__ __launch_bounds__(256) void scan1_kernel(const int* __restrict__ cnt,
                                                    int* __restrict__ rowptr,
                                                    int* __restrict__ bsum, int n) {
  __shared__ int s[256];
  const int t = threadIdx.x;
  const int base = blockIdx.x * 1024 + t * 4;
  int v0, v1, v2, v3;
  if (base + 3 < n) {
    int4 v = *(const int4*)(cnt + base);
    v0 = v.x; v1 = v.y; v2 = v.z; v3 = v.w;
  } else {
    v0 = (base + 0 < n) ? cnt[base + 0] : 0;
    v1 = (base + 1 < n) ? cnt[base + 1] : 0;
    v2 = (base + 2 < n) ? cnt[base + 2] : 0;
    v3 = (base + 3 < n) ? cnt[base + 3] : 0;
  }
  int tot = v0 + v1 + v2 + v3;
  s[t] = tot;
  __syncthreads();
  for (int off = 1; off < 256; off <<= 1) {
    int x = (t >= off) ? s[t - off] : 0;
    __syncthreads();
    s[t] += x;
    __syncthreads();
  }
  int excl = s[t] - tot;
  if (t == 255) bsum[blockIdx.x] = s[t];
  if (base + 0 < n) rowptr[base + 0] = excl;
  if (base + 1 < n) rowptr[base + 1] = excl + v0;
  if (base + 2 < n) rowptr[base + 2] = excl + v0 + v1;
  if (base + 3 < n) rowptr[base + 3] = excl + v0 + v1 + v2;
}

__global__ __launch_bounds__(256) void scanP_kernel(int* __restrict__ bsum,
                                                    int* __restrict__ boff,
                                                    int nb, int* __restrict__ rowptr,
                                                    int n, int ne) {
  __shared__ int s[256];
  const int t = threadIdx.x;
  int v = (t < nb) ? bsum[t] : 0;
  s[t] = v;
  __syncthreads();
  for (int off = 1; off < 256; off <<= 1) {
    int x = (t >= off) ? s[t - off] : 0;
    __syncthreads();
    s[t] += x;
    __syncthreads();
  }
  if (t < nb) boff[t] = s[t] - v;
  if (t == 0) rowptr[n] = ne;
}

// adds block offsets; computes dinv; zeroes cnt for reuse as fill cursor
__global__ void scan2_kernel(int* __restrict__ rowptr, const int* __restrict__ boff,
                             int* __restrict__ cnt, float* __restrict__ dinv, int n) {
  int i = blockIdx.x * blockDim.x + threadIdx.x;
  if (i < n) {
    rowptr[i] += boff[i >> 10];
    float d = (float)cnt[i] + 1.0f;
    dinv[i] = 1.0f / sqrtf(d);
    cnt[i] = 0;
  }
}

// counting-sort fill: dst-sorted src indices (uint16, n < 65536)
__global__ void fill_kernel(const int* __restrict__ srcI, const int* __restrict__ dstI,
                            const int* __restrict__ rowptr, int* __restrict__ cnt,
                            unsigned short* __restrict__ ssrc, int ne) {
  int e = blockIdx.x * blockDim.x + threadIdx.x;
  if (e >= ne) return;
  int s = srcI[e], d = dstI[e];
  int pos = rowptr[d] + atomicAdd(&cnt[d], 1);
  ssrc[pos] = (unsigned short)s;
}

// ---------------- tiled GEMM: Y[n][64] = concat(X1,X2)@W * dinv, fp16 out ----------------
// 128 nodes/block, 256 threads, thread tile = 4 nodes x 8 cols.
struct alignas(16) half8 { __half h[8]; };

template<int IN1, int IN2, bool DUALW>
__global__ __launch_bounds__(256) void gemm_kernel(
    const float* __restrict__ X1, const float* __restrict__ X2,
    const float* __restrict__ Wa, const float* __restrict__ Wb,
    const float* __restrict__ dinv, __half* __restrict__ Y, int n) {
  constexpr int IN = IN1 + IN2;
  constexpr int IP = IN + 4;       // padded stride (16B-aligned rows, 2-way banks only)
  __shared__ float xs[128 * IP];
  __shared__ float ws[IN * 64];

  const int tid = threadIdx.x;
  const int base = blockIdx.x * 128;

  // stage W
  for (int i = tid; i < IN * 64; i += 256) {
    if (DUALW) {
      int k = i >> 6, c = i & 63;
      ws[i] = (c < 32) ? Wa[k * 32 + c] : Wb[k * 32 + (c - 32)];
    } else {
      ws[i] = Wa[i];
    }
  }
  // stage X1 (float4 coalesced)
  for (int idx = tid; idx < 128 * (IN1 / 4); idx += 256) {
    int node = idx / (IN1 / 4);
    int k4 = (idx % (IN1 / 4)) * 4;
    int g = base + node;
    float4 v = (g < n) ? *(const float4*)(X1 + (size_t)g * IN1 + k4)
                       : make_float4(0.f, 0.f, 0.f, 0.f);
    *(float4*)&xs[node * IP + k4] = v;
  }
  // stage X2
  if (IN2 > 0) {
    for (int idx = tid; idx < 128 * (IN2 / 4); idx += 256) {
      int node = idx / (IN2 / 4);
      int k4 = (idx % (IN2 / 4)) * 4;
      int g = base + node;
      float4 v = (g < n) ? *(const float4*)(X2 + (size_t)g * IN2 + k4)
                         : make_float4(0.f, 0.f, 0.f, 0.f);
      *(float4*)&xs[node * IP + IN1 + k4] = v;
    }
  }
  __syncthreads();

  const int c8 = (tid & 7) * 8;         // col base (8 cols)
  const int r4 = (tid >> 3) * 4;        // node base (4 nodes)
  float acc[4][8];
#pragma unroll
  for (int i = 0; i < 4; ++i)
#pragma unroll
    for (int c = 0; c < 8; ++c) acc[i][c] = 0.0f;

#pragma unroll 2
  for (int kk = 0; kk < IN; kk += 4) {
    float4 xv[4];
    float4 wv[4][2];
#pragma unroll
    for (int i = 0; i < 4; ++i) xv[i] = *(const float4*)&xs[(r4 + i) * IP + kk];
#pragma unroll
    for (int j = 0; j < 4; ++j) {
      wv[j][0] = *(const float4*)&ws[(kk + j) * 64 + c8];
      wv[j][1] = *(const float4*)&ws[(kk + j) * 64 + c8 + 4];
    }
#pragma unroll
    for (int i = 0; i < 4; ++i) {
      const float* xi = (const float*)&xv[i];
#pragma unroll
      for (int j = 0; j < 4; ++j) {
        const float* wj = (const float*)&wv[j][0];
#pragma unroll
        for (int c = 0; c < 8; ++c) {
          acc[i][c] = fmaf(xi[j], wj[c], acc[i][c]);
        }
      }
    }
  }

#pragma unroll
  for (int i = 0; i < 4; ++i) {
    int g = base + r4 + i;
    if (g < n) {
      float dv = dinv[g];
      half8 o;
#pragma unroll
      for (int c = 0; c < 8; ++c) o.h[c] = __float2half(acc[i][c] * dv);
      *(half8*)&Y[(size_t)g * 64 + c8] = o;
    }
  }
}

// ---------------- CSR gather + fused finalize (half2 lanes, 8-deep ILP) ----------------
// one wave per node. lane = hf*32 + cl; cl covers cols (2cl, 2cl+1).
// half 0 accumulates even-parity edges (+self), half 1 odd-parity; combined via shfl^32.
// 8 edges in flight per iteration (4 accumulator pairs x 2 lane halves).
// MODE 0: +bias, relu -> out. MODE 1: mean||logvar packed -> z/mean/logvar. MODE 2: +bias -> out
template<int MODE>
__global__ __launch_bounds__(256) void gather_kernel(
    const int* __restrict__ rowptr, const unsigned short* __restrict__ ssrc,
    const __half* __restrict__ xwp, const float* __restrict__ dinv,
    const float* __restrict__ b0, const float* __restrict__ b1,
    float* __restrict__ out, int n) {
  const int node = (blockIdx.x * 256 + threadIdx.x) >> 6;
  const int lane = threadIdx.x & 63;
  if (node >= n) return;
  const int hf = lane >> 5;       // edge parity handled by this lane
  const int cl = lane & 31;       // column pair index

  float2 a1, a2, a3, a4;
  a2.x = a2.y = a3.x = a3.y = a4.x = a4.y = 0.f;
  {
    float2 f = __half22float2(((const __half2*)(xwp + (size_t)node * 64))[cl]);
    a1.x = hf ? 0.f : f.x;
    a1.y = hf ? 0.f : f.y;
  }

  const int beg = rowptr[node];
  const int end = rowptr[node + 1];
  for (int cbase = beg; cbase < end; cbase += 64) {
    int m = end - cbase; if (m > 64) m = 64;
    unsigned sv = (lane < m) ? (unsigned)ssrc[cbase + lane] : 0u;
    int k = 0;
    for (; k + 7 < m; k += 8) {
      unsigned sa = __shfl(sv, k + 0 + hf, 64);
      unsigned sb = __shfl(sv, k + 2 + hf, 64);
      unsigned sc = __shfl(sv, k + 4 + hf, 64);
      unsigned sd = __shfl(sv, k + 6 + hf, 64);
      float2 fa = __half22float2(((const __half2*)(xwp + (size_t)sa * 64))[cl]);
      float2 fb = __half22float2(((const __half2*)(xwp + (size_t)sb * 64))[cl]);
      float2 fc = __half22float2(((const __half2*)(xwp + (size_t)sc * 64))[cl]);
      float2 fd = __half22float2(((const __half2*)(xwp + (size_t)sd * 64))[cl]);
      a1.x += fa.x; a1.y += fa.y;
      a2.x += fb.x; a2.y += fb.y;
      a3.x += fc.x; a3.y += fc.y;
      a4.x += fd.x; a4.y += fd.y;
    }
    for (; k + 1 < m; k += 2) {
      unsigned sa = __shfl(sv, k + hf, 64);
      float2 fa = __half22float2(((const __half2*)(xwp + (size_t)sa * 64))[cl]);
      a1.x += fa.x; a1.y += fa.y;
    }
    if (k < m) {  // single tail edge -> half 0 only
      unsigned sa = __shfl(sv, k, 64);
      if (hf == 0) {
        float2 fa = __half22float2(((const __half2*)(xwp + (size_t)sa * 64))[cl]);
        a1.x += fa.x; a1.y += fa.y;
      }
    }
  }
  float2 acc;
  acc.x = (a1.x + a2.x) + (a3.x + a4.x);
  acc.y = (a1.y + a2.y) + (a3.y + a4.y);
  // combine lane halves (lane ^ 32 holds the other parity's partial)
  acc.x += __shfl(acc.x, lane ^ 32, 64);
  acc.y += __shfl(acc.y, lane ^ 32, 64);
  float dv = dinv[node];
  float vx = acc.x * dv, vy = acc.y * dv;

  if (hf != 0) return;  // lanes 0..31 write

  const int c0 = 2 * cl;
  if (MODE == 0) {
    float2 o;
    o.x = fmaxf(vx + b0[c0], 0.0f);
    o.y = fmaxf(vy + b0[c0 + 1], 0.0f);
    ((float2*)(out + (size_t)node * 64))[cl] = o;
  } else if (MODE == 2) {
    float2 o;
    o.x = vx + b0[c0];
    o.y = vy + b0[c0 + 1];
    ((float2*)(out + (size_t)node * 64))[cl] = o;
  } else {
    // MODE 1: cols 0..31 mean (cl<16), cols 32..63 logvar (cl>=16)
    float bx = (c0 < 32) ? b0[c0] : b1[c0 - 32];
    float by = (c0 + 1 < 32) ? b0[c0 + 1] : b1[c0 + 1 - 32];
    vx += bx; vy += by;
    // partner: lane cl+16 holds cols (c0+32, c0+33)
    float ox = __shfl(vx, lane + 16, 64);
    float oy = __shfl(vy, lane + 16, 64);
    const int NZ = n * 32;
    if (cl < 16) {
      int j = node * 32 + c0;
      float n0 = jax_normal_at((unsigned)j);
      float n1 = jax_normal_at((unsigned)(j + 1));
      out[j]     = fmaf(n0, expf(0.5f * ox), vx);  // z
      out[j + 1] = fmaf(n1, expf(0.5f * oy), vy);
      out[NZ + j]     = vx;                        // mean
      out[NZ + j + 1] = vy;
    } else {
      int j = node * 32 + (c0 - 32);
      out[2 * NZ + j]     = vx;                    // logvar
      out[2 * NZ + j + 1] = vy;
    }
  }
}

// ---------------- launch ----------------

extern "C" void kernel_launch(void* const* d_in, const int* in_sizes, int n_in,
                              void* d_out, int out_size, void* d_ws, size_t ws_size,
                              hipStream_t stream) {
  const float* feat = (const float*)d_in[0];
  const float* cond = (const float*)d_in[1];
  const int*   eidx = (const int*)d_in[2];
  const float* W1  = (const float*)d_in[3];
  const float* b1  = (const float*)d_in[4];
  const float* Wm  = (const float*)d_in[5];
  const float* bm  = (const float*)d_in[6];
  const float* Wlv = (const float*)d_in[7];
  const float* blv = (const float*)d_in[8];
  const float* Wd  = (const float*)d_in[9];
  const float* bd  = (const float*)d_in[10];
  const float* Wo  = (const float*)d_in[11];
  const float* bo  = (const float*)d_in[12];

  const int n  = in_sizes[0] / 64;   // 50000 (< 65536 -> ssrc fits uint16)
  const int ne = in_sizes[2] / 2;    // 800000
  const int* srcI = eidx;
  const int* dstI = eidx + ne;

  // workspace carve-up (keep 4B alignment)
  int*   cnt    = (int*)d_ws;                     // n
  int*   rowptr = cnt + n;                        // n+1
  int*   bsum   = rowptr + n + 1;                 // 256
  int*   boff   = bsum + 256;                     // 256
  float* dinv   = (float*)(boff + 256);           // n
  __half* xwp   = (__half*)(dinv + n);            // n*64 halves
  float* h      = (float*)(xwp + (size_t)n * 64); // n*64 floats
  unsigned short* ssrc = (unsigned short*)(h + (size_t)n * 64); // ne

  float* dout   = (float*)d_out;
  float* zbuf   = dout;                        // n*32
  float* outbuf = dout + (size_t)3 * n * 32;   // n*64

  const int BT = 256;
  auto blk = [](long long t) { return (int)((t + 255) / 256); };
  const int nb_n  = blk(n);
  const int nb_e  = blk(ne);
  const int nb_sc = (n + 1023) / 1024;
  const int nb_gw = blk((long long)n * 64);
  const int nb_g  = (n + 127) / 128;

  // ---- CSR setup ----
  hipLaunchKernelGGL(zero_i_kernel, dim3(nb_n), dim3(BT), 0, stream, cnt, n);
  hipLaunchKernelGGL(degree_i_kernel, dim3(nb_e), dim3(BT), 0, stream, dstI, cnt, ne);
  hipLaunchKernelGGL(scan1_kernel, dim3(nb_sc), dim3(BT), 0, stream, cnt, rowptr, bsum, n);
  hipLaunchKernelGGL(scanP_kernel, dim3(1), dim3(BT), 0, stream, bsum, boff, nb_sc, rowptr, n, ne);
  hipLaunchKernelGGL(scan2_kernel, dim3(nb_n), dim3(BT), 0, stream, rowptr, boff, cnt, dinv, n);
  hipLaunchKernelGGL(fill_kernel, dim3(nb_e), dim3(BT), 0, stream,
                     srcI, dstI, rowptr, cnt, ssrc, ne);

  // ---- encoder conv1: h = relu(gcn(concat(feat,cond), W1, b1)) ----
  hipLaunchKernelGGL((gemm_kernel<64, 32, false>), dim3(nb_g), dim3(BT), 0, stream,
                     feat, cond, W1, nullptr, dinv, xwp, n);
  hipLaunchKernelGGL((gather_kernel<0>), dim3(nb_gw), dim3(BT), 0, stream,
                     rowptr, ssrc, xwp, dinv, b1, nullptr, h, n);

  // ---- mean/logvar packed conv + reparam z ----
  hipLaunchKernelGGL((gemm_kernel<64, 0, true>), dim3(nb_g), dim3(BT), 0, stream,
                     h, nullptr, Wm, Wlv, dinv, xwp, n);
  hipLaunchKernelGGL((gather_kernel<1>), dim3(nb_gw), dim3(BT), 0, stream,
                     rowptr, ssrc, xwp, dinv, bm, blv, dout, n);

  // ---- decoder conv1: hd = relu(gcn(concat(z,cond), Wd, bd)) ----
  hipLaunchKernelGGL((gemm_kernel<32, 32, false>), dim3(nb_g), dim3(BT), 0, stream,
                     zbuf, cond, Wd, nullptr, dinv, xwp, n);
  hipLaunchKernelGGL((gather_kernel<0>), dim3(nb_gw), dim3(BT), 0, stream,
                     rowptr, ssrc, xwp, dinv, bd, nullptr, h, n);

  // ---- decoder out conv ----
  hipLaunchKernelGGL((gemm_kernel<64, 0, false>), dim3(nb_g), dim3(BT), 0, stream,
                     h, nullptr, Wo, nullptr, dinv, xwp, n);
  hipLaunchKernelGGL((gather_kernel<2>), dim3(nb_gw), dim3(BT), 0, stream,
                     rowptr, ssrc, xwp, dinv, bo, nullptr, outbuf, n);
}

// Round 8
// 247.957 us; speedup vs baseline: 3.7483x; 1.1023x over previous
//
#include <hip/hip_runtime.h>
#include <hip/hip_bf16.h>
#include <hip/hip_fp16.h>
#include <math.h>

typedef _Float16 f16;
typedef __attribute__((ext_vector_type(8))) _Float16 f16x8;
typedef __attribute__((ext_vector_type(4))) float f32x4;

// ---------------- JAX threefry2x32 (partitionable) + normal ----------------

static __device__ __forceinline__ unsigned rotl32(unsigned x, int d) {
  return (x << d) | (x >> (32 - d));
}

// key = (0, 42)  == jax.random.key(42)
static __device__ __forceinline__ void threefry_0_42(unsigned& x0, unsigned& x1) {
  const unsigned ks0 = 0u, ks1 = 42u, ks2 = 0u ^ 42u ^ 0x1BD11BDAu;
  x0 += ks0; x1 += ks1;
#define TF_R(r) { x0 += x1; x1 = rotl32(x1, (r)); x1 ^= x0; }
  TF_R(13) TF_R(15) TF_R(26) TF_R(6)
  x0 += ks1; x1 += ks2 + 1u;
  TF_R(17) TF_R(29) TF_R(16) TF_R(24)
  x0 += ks2; x1 += ks0 + 2u;
  TF_R(13) TF_R(15) TF_R(26) TF_R(6)
  x0 += ks0; x1 += ks1 + 3u;
  TF_R(17) TF_R(29) TF_R(16) TF_R(24)
  x0 += ks1; x1 += ks2 + 4u;
  TF_R(13) TF_R(15) TF_R(26) TF_R(6)
  x0 += ks2; x1 += ks0 + 5u;
#undef TF_R
}

static __device__ __forceinline__ float erfinv_f(float u) {
  float w = -logf((1.0f - u) * (1.0f + u));
  float p;
  if (w < 5.0f) {
    w = w - 2.5f;
    p = 2.81022636e-08f;
    p = fmaf(p, w, 3.43273939e-07f);
    p = fmaf(p, w, -3.5233877e-06f);
    p = fmaf(p, w, -4.39150654e-06f);
    p = fmaf(p, w, 0.00021858087f);
    p = fmaf(p, w, -0.00125372503f);
    p = fmaf(p, w, -0.00417768164f);
    p = fmaf(p, w, 0.246640727f);
    p = fmaf(p, w, 1.50140941f);
  } else {
    w = sqrtf(w) - 3.0f;
    p = -0.000200214257f;
    p = fmaf(p, w, 0.000100950558f);
    p = fmaf(p, w, 0.00134934322f);
    p = fmaf(p, w, -0.00367342844f);
    p = fmaf(p, w, 0.00573950773f);
    p = fmaf(p, w, -0.0076224613f);
    p = fmaf(p, w, 0.00943887047f);
    p = fmaf(p, w, 1.00167406f);
    p = fmaf(p, w, 2.83297682f);
  }
  return p * u;
}

// jax_threefry_partitionable=True: bits(j) = xor(threefry2x32(key, (0, j)))
static __device__ __forceinline__ float jax_normal_at(unsigned j) {
  unsigned x0 = 0u, x1 = j;
  threefry_0_42(x0, x1);
  unsigned bits = x0 ^ x1;
  float f = __uint_as_float((bits >> 9) | 0x3f800000u) - 1.0f;   // [0,1)
  float u = fmaf(f, 1.99999994f, -0.99999994f);
  return 1.41421356237f * erfinv_f(u);
}

// ---------------- setup kernels ----------------

__global__ void zero_i_kernel(int* __restrict__ p, int n) {
  int i = blockIdx.x * blockDim.x + threadIdx.x;
  if (i < n) p[i] = 0;
}

__global__ void degree_i_kernel(const int* __restrict__ dstI, int* __restrict__ cnt, int ne) {
  int e = blockIdx.x * blockDim.x + threadIdx.x;
  if (e < ne) atomicAdd(&cnt[dstI[e]], 1);
}

// ---- exclusive scan of cnt[n] -> rowptr ----
__global__ __launch_bounds__(256) void scan1_kernel(const int* __restrict__ cnt,
                                                    int* __restrict__ rowptr,
                                                    int* __restrict__ bsum, int n) {
  __shared__ int s[256];
  const int t = threadIdx.x;
  const int base = blockIdx.x * 1024 + t * 4;
  int v0, v1, v2, v3;
  if (base + 3 < n) {
    int4 v = *(const int4*)(cnt + base);
    v0 = v.x; v1 = v.y; v2 = v.z; v3 = v.w;
  } else {
    v0 = (base + 0 < n) ? cnt[base + 0] : 0;
    v1 = (base + 1 < n) ? cnt[base + 1] : 0;
    v2 = (base + 2 < n) ? cnt[base + 2] : 0;
    v3 = (base + 3 < n) ? cnt[base + 3] : 0;
  }
  int tot = v0 + v1 + v2 + v3;
  s[t] = tot;
  __syncthreads();
  for (int off = 1; off < 256; off <<= 1) {
    int x = (t >= off) ? s[t - off] : 0;
    __syncthreads();
    s[t] += x;
    __syncthreads();
  }
  int excl = s[t] - tot;
  if (t == 255) bsum[blockIdx.x] = s[t];
  if (base + 0 < n) rowptr[base + 0] = excl;
  if (base + 1 < n) rowptr[base + 1] = excl + v0;
  if (base + 2 < n) rowptr[base + 2] = excl + v0 + v1;
  if (base + 3 < n) rowptr[base + 3] = excl + v0 + v1 + v2;
}

__global__ __launch_bounds__(256) void scanP_kernel(int* __restrict__ bsum,
                                                    int* __restrict__ boff,
                                                    int nb, int* __restrict__ rowptr,
                                                    int n, int ne) {
  __shared__ int s[256];
  const int t = threadIdx.x;
  int v = (t < nb) ? bsum[t] : 0;
  s[t] = v;
  __syncthreads();
  for (int off = 1; off < 256; off <<= 1) {
    int x = (t >= off) ? s[t - off] : 0;
    __syncthreads();
    s[t] += x;
    __syncthreads();
  }
  if (t < nb) boff[t] = s[t] - v;
  if (t == 0) rowptr[n] = ne;
}

// adds block offsets; computes dinv; zeroes cnt for reuse as fill cursor
__global__ void scan2_kernel(int* __restrict__ rowptr, const int* __restrict__ boff,
                             int* __restrict__ cnt, float* __restrict__ dinv, int n) {
  int i = blockIdx.x * blockDim.x + threadIdx.x;
  if (i < n) {
    rowptr[i] += boff[i >> 10];
    float d = (float)cnt[i] + 1.0f;
    dinv[i] = 1.0f / sqrtf(d);
    cnt[i] = 0;
  }
}

// counting-sort fill: dst-sorted src indices (uint16, n < 65536)
__global__ void fill_kernel(const int* __restrict__ srcI, const int* __restrict__ dstI,
                            const int* __restrict__ rowptr, int* __restrict__ cnt,
                            unsigned short* __restrict__ ssrc, int ne) {
  int e = blockIdx.x * blockDim.x + threadIdx.x;
  if (e >= ne) return;
  int s = srcI[e], d = dstI[e];
  int pos = rowptr[d] + atomicAdd(&cnt[d], 1);
  ssrc[pos] = (unsigned short)s;
}

// ---------------- MFMA GEMM: Y[n][64] = fp16(concat(X1,X2)) @ fp16(W) * dinv ----------------
// 128 nodes/block, 4 waves; wave = 32 rows x 64 cols; K-step 32 via mfma_f32_16x16x32_f16.
// A frag: row = lane&15, k = (lane>>4)*8 + j. B frag: col = lane&15, same k (from W^T in LDS).
// C/D: col = lane&15, row = (lane>>4)*4 + reg  [m89-verified layout].
template<int IN1, int IN2, bool X1HALF, bool DUALW>
__global__ __launch_bounds__(256) void gemm_mfma_kernel(
    const void* __restrict__ X1v, const float* __restrict__ X2,
    const float* __restrict__ Wa, const float* __restrict__ Wb,
    const float* __restrict__ dinv, __half* __restrict__ Y, int n) {
  constexpr int IN = IN1 + IN2;
  constexpr int IP = IN + 8;   // padded stride in halves: 16-lane frag reads hit 8 banks 2-way (free)
  __shared__ f16 xs[128 * IP];
  __shared__ f16 wt[64 * IP];  // W transposed: wt[col][k]

  const int tid = threadIdx.x;
  const int base = blockIdx.x * 128;

  // stage W^T (fp32 -> fp16)
  for (int i = tid; i < IN * 64; i += 256) {
    int k = i >> 6, c = i & 63;
    float w;
    if (DUALW) w = (c < 32) ? Wa[k * 32 + c] : Wb[k * 32 + (c - 32)];
    else       w = Wa[i];
    wt[c * IP + k] = (f16)w;
  }
  // stage X1
  if (X1HALF) {
    const __half* X1 = (const __half*)X1v;
    for (int idx = tid; idx < 128 * (IN1 / 8); idx += 256) {
      int node = idx / (IN1 / 8);
      int k8 = (idx % (IN1 / 8)) * 8;
      int g = base + node;
      f16x8 v = {};
      if (g < n) v = *(const f16x8*)(X1 + (size_t)g * IN1 + k8);
      *(f16x8*)&xs[node * IP + k8] = v;
    }
  } else {
    const float* X1 = (const float*)X1v;
    for (int idx = tid; idx < 128 * (IN1 / 4); idx += 256) {
      int node = idx / (IN1 / 4);
      int k4 = (idx % (IN1 / 4)) * 4;
      int g = base + node;
      float4 v = (g < n) ? *(const float4*)(X1 + (size_t)g * IN1 + k4)
                         : make_float4(0.f, 0.f, 0.f, 0.f);
      f16* p = &xs[node * IP + k4];
      p[0] = (f16)v.x; p[1] = (f16)v.y; p[2] = (f16)v.z; p[3] = (f16)v.w;
    }
  }
  // stage X2 (always fp32)
  if (IN2 > 0) {
    for (int idx = tid; idx < 128 * (IN2 / 4); idx += 256) {
      int node = idx / (IN2 / 4);
      int k4 = (idx % (IN2 / 4)) * 4;
      int g = base + node;
      float4 v = (g < n) ? *(const float4*)(X2 + (size_t)g * IN2 + k4)
                         : make_float4(0.f, 0.f, 0.f, 0.f);
      f16* p = &xs[node * IP + IN1 + k4];
      p[0] = (f16)v.x; p[1] = (f16)v.y; p[2] = (f16)v.z; p[3] = (f16)v.w;
    }
  }
  __syncthreads();

  const int wid  = tid >> 6;
  const int lane = tid & 63;
  const int l15  = lane & 15;
  const int lk8  = (lane >> 4) * 8;

  f32x4 acc[2][4] = {{{0.f,0.f,0.f,0.f}}};
  constexpr int KB = IN / 32;
#pragma unroll
  for (int kb = 0; kb < KB; ++kb) {
    const int k0 = kb * 32 + lk8;
    f16x8 a0 = *(const f16x8*)&xs[(wid * 32 +      l15) * IP + k0];
    f16x8 a1 = *(const f16x8*)&xs[(wid * 32 + 16 + l15) * IP + k0];
#pragma unroll
    for (int ct = 0; ct < 4; ++ct) {
      f16x8 b = *(const f16x8*)&wt[(ct * 16 + l15) * IP + k0];
      acc[0][ct] = __builtin_amdgcn_mfma_f32_16x16x32_f16(a0, b, acc[0][ct], 0, 0, 0);
      acc[1][ct] = __builtin_amdgcn_mfma_f32_16x16x32_f16(a1, b, acc[1][ct], 0, 0, 0);
    }
  }

#pragma unroll
  for (int rt = 0; rt < 2; ++rt) {
#pragma unroll
    for (int i = 0; i < 4; ++i) {
      int node = base + wid * 32 + rt * 16 + (lane >> 4) * 4 + i;
      if (node < n) {
        float dv = dinv[node];
#pragma unroll
        for (int ct = 0; ct < 4; ++ct) {
          Y[(size_t)node * 64 + ct * 16 + l15] = __float2half(acc[rt][ct][i] * dv);
        }
      }
    }
  }
}

// ---------------- CSR gather + fused finalize (half2 lanes, 8-deep ILP) ----------------
// MODE 0: +bias, relu -> __half out. MODE 1: mean||logvar -> z/mean/logvar (fp32).
// MODE 2: +bias -> fp32 out.
template<int MODE>
__global__ __launch_bounds__(256) void gather_kernel(
    const int* __restrict__ rowptr, const unsigned short* __restrict__ ssrc,
    const __half* __restrict__ xwp, const float* __restrict__ dinv,
    const float* __restrict__ b0, const float* __restrict__ b1,
    void* __restrict__ outv, int n) {
  const int node = (blockIdx.x * 256 + threadIdx.x) >> 6;
  const int lane = threadIdx.x & 63;
  if (node >= n) return;
  const int hf = lane >> 5;       // edge parity handled by this lane
  const int cl = lane & 31;       // column pair index

  float2 a1, a2, a3, a4;
  a2.x = a2.y = a3.x = a3.y = a4.x = a4.y = 0.f;
  {
    float2 f = __half22float2(((const __half2*)(xwp + (size_t)node * 64))[cl]);
    a1.x = hf ? 0.f : f.x;
    a1.y = hf ? 0.f : f.y;
  }

  const int beg = rowptr[node];
  const int end = rowptr[node + 1];
  for (int cbase = beg; cbase < end; cbase += 64) {
    int m = end - cbase; if (m > 64) m = 64;
    unsigned sv = (lane < m) ? (unsigned)ssrc[cbase + lane] : 0u;
    int k = 0;
    for (; k + 7 < m; k += 8) {
      unsigned sa = __shfl(sv, k + 0 + hf, 64);
      unsigned sb = __shfl(sv, k + 2 + hf, 64);
      unsigned sc = __shfl(sv, k + 4 + hf, 64);
      unsigned sd = __shfl(sv, k + 6 + hf, 64);
      float2 fa = __half22float2(((const __half2*)(xwp + (size_t)sa * 64))[cl]);
      float2 fb = __half22float2(((const __half2*)(xwp + (size_t)sb * 64))[cl]);
      float2 fc = __half22float2(((const __half2*)(xwp + (size_t)sc * 64))[cl]);
      float2 fd = __half22float2(((const __half2*)(xwp + (size_t)sd * 64))[cl]);
      a1.x += fa.x; a1.y += fa.y;
      a2.x += fb.x; a2.y += fb.y;
      a3.x += fc.x; a3.y += fc.y;
      a4.x += fd.x; a4.y += fd.y;
    }
    for (; k + 1 < m; k += 2) {
      unsigned sa = __shfl(sv, k + hf, 64);
      float2 fa = __half22float2(((const __half2*)(xwp + (size_t)sa * 64))[cl]);
      a1.x += fa.x; a1.y += fa.y;
    }
    if (k < m) {  // single tail edge -> half 0 only
      unsigned sa = __shfl(sv, k, 64);
      if (hf == 0) {
        float2 fa = __half22float2(((const __half2*)(xwp + (size_t)sa * 64))[cl]);
        a1.x += fa.x; a1.y += fa.y;
      }
    }
  }
  float2 acc;
  acc.x = (a1.x + a2.x) + (a3.x + a4.x);
  acc.y = (a1.y + a2.y) + (a3.y + a4.y);
  acc.x += __shfl(acc.x, lane ^ 32, 64);
  acc.y += __shfl(acc.y, lane ^ 32, 64);
  float dv = dinv[node];
  float vx = acc.x * dv, vy = acc.y * dv;

  if (hf != 0) return;  // lanes 0..31 write

  const int c0 = 2 * cl;
  if (MODE == 0) {
    __half* out = (__half*)outv;
    __half2 o = __floats2half2_rn(fmaxf(vx + b0[c0], 0.0f), fmaxf(vy + b0[c0 + 1], 0.0f));
    ((__half2*)(out + (size_t)node * 64))[cl] = o;
  } else if (MODE == 2) {
    float* out = (float*)outv;
    float2 o;
    o.x = vx + b0[c0];
    o.y = vy + b0[c0 + 1];
    ((float2*)(out + (size_t)node * 64))[cl] = o;
  } else {
    float* out = (float*)outv;
    // MODE 1: cols 0..31 mean (cl<16), cols 32..63 logvar (cl>=16)
    float bx = (c0 < 32) ? b0[c0] : b1[c0 - 32];
    float by = (c0 + 1 < 32) ? b0[c0 + 1] : b1[c0 + 1 - 32];
    vx += bx; vy += by;
    float ox = __shfl(vx, lane + 16, 64);
    float oy = __shfl(vy, lane + 16, 64);
    const int NZ = n * 32;
    if (cl < 16) {
      int j = node * 32 + c0;
      float n0 = jax_normal_at((unsigned)j);
      float n1 = jax_normal_at((unsigned)(j + 1));
      out[j]     = fmaf(n0, expf(0.5f * ox), vx);  // z
      out[j + 1] = fmaf(n1, expf(0.5f * oy), vy);
      out[NZ + j]     = vx;                        // mean
      out[NZ + j + 1] = vy;
    } else {
      int j = node * 32 + (c0 - 32);
      out[2 * NZ + j]     = vx;                    // logvar
      out[2 * NZ + j + 1] = vy;
    }
  }
}

// ---------------- launch ----------------

extern "C" void kernel_launch(void* const* d_in, const int* in_sizes, int n_in,
                              void* d_out, int out_size, void* d_ws, size_t ws_size,
                              hipStream_t stream) {
  const float* feat = (const float*)d_in[0];
  const float* cond = (const float*)d_in[1];
  const int*   eidx = (const int*)d_in[2];
  const float* W1  = (const float*)d_in[3];
  const float* b1  = (const float*)d_in[4];
  const float* Wm  = (const float*)d_in[5];
  const float* bm  = (const float*)d_in[6];
  const float* Wlv = (const float*)d_in[7];
  const float* blv = (const float*)d_in[8];
  const float* Wd  = (const float*)d_in[9];
  const float* bd  = (const float*)d_in[10];
  const float* Wo  = (const float*)d_in[11];
  const float* bo  = (const float*)d_in[12];

  const int n  = in_sizes[0] / 64;   // 50000 (< 65536 -> ssrc fits uint16)
  const int ne = in_sizes[2] / 2;    // 800000
  const int* srcI = eidx;
  const int* dstI = eidx + ne;

  // workspace carve-up (keep 16B alignment for int4 loads)
  int*   cnt    = (int*)d_ws;                     // n
  int*   rowptr = cnt + n;                        // n+1
  int*   bsum   = rowptr + n + 1;                 // 256 (+pad)
  int*   boff   = bsum + 256;                     // 256
  float* dinv   = (float*)(boff + 256 + 3);       // n
  __half* xwp   = (__half*)(dinv + n);            // n*64
  __half* h     = xwp + (size_t)n * 64;           // n*64
  unsigned short* ssrc = (unsigned short*)(h + (size_t)n * 64); // ne

  float* dout   = (float*)d_out;
  float* zbuf   = dout;                        // n*32
  float* outbuf = dout + (size_t)3 * n * 32;   // n*64

  const int BT = 256;
  auto blk = [](long long t) { return (int)((t + 255) / 256); };
  const int nb_n  = blk(n);
  const int nb_e  = blk(ne);
  const int nb_sc = (n + 1023) / 1024;
  const int nb_gw = blk((long long)n * 64);
  const int nb_g  = (n + 127) / 128;

  // ---- CSR setup ----
  hipLaunchKernelGGL(zero_i_kernel, dim3(nb_n), dim3(BT), 0, stream, cnt, n);
  hipLaunchKernelGGL(degree_i_kernel, dim3(nb_e), dim3(BT), 0, stream, dstI, cnt, ne);
  hipLaunchKernelGGL(scan1_kernel, dim3(nb_sc), dim3(BT), 0, stream, cnt, rowptr, bsum, n);
  hipLaunchKernelGGL(scanP_kernel, dim3(1), dim3(BT), 0, stream, bsum, boff, nb_sc, rowptr, n, ne);
  hipLaunchKernelGGL(scan2_kernel, dim3(nb_n), dim3(BT), 0, stream, rowptr, boff, cnt, dinv, n);
  hipLaunchKernelGGL(fill_kernel, dim3(nb_e), dim3(BT), 0, stream,
                     srcI, dstI, rowptr, cnt, ssrc, ne);

  // ---- encoder conv1: h = relu(gcn(concat(feat,cond), W1, b1)) ----
  hipLaunchKernelGGL((gemm_mfma_kernel<64, 32, false, false>), dim3(nb_g), dim3(BT), 0, stream,
                     feat, cond, W1, nullptr, dinv, xwp, n);
  hipLaunchKernelGGL((gather_kernel<0>), dim3(nb_gw), dim3(BT), 0, stream,
                     rowptr, ssrc, xwp, dinv, b1, nullptr, h, n);

  // ---- mean/logvar packed conv + reparam z ----
  hipLaunchKernelGGL((gemm_mfma_kernel<64, 0, true, true>), dim3(nb_g), dim3(BT), 0, stream,
                     h, nullptr, Wm, Wlv, dinv, xwp, n);
  hipLaunchKernelGGL((gather_kernel<1>), dim3(nb_gw), dim3(BT), 0, stream,
                     rowptr, ssrc, xwp, dinv, bm, blv, dout, n);

  // ---- decoder conv1: hd = relu(gcn(concat(z,cond), Wd, bd)) ----
  hipLaunchKernelGGL((gemm_mfma_kernel<32, 32, false, false>), dim3(nb_g), dim3(BT), 0, stream,
                     zbuf, cond, Wd, nullptr, dinv, xwp, n);
  hipLaunchKernelGGL((gather_kernel<0>), dim3(nb_gw), dim3(BT), 0, stream,
                     rowptr, ssrc, xwp, dinv, bd, nullptr, h, n);

  // ---- decoder out conv ----
  hipLaunchKernelGGL((gemm_mfma_kernel<64, 0, true, false>), dim3(nb_g), dim3(BT), 0, stream,
                     h, nullptr, Wo, nullptr, dinv, xwp, n);
  hipLaunchKernelGGL((gather_kernel<2>), dim3(nb_gw), dim3(BT), 0, stream,
                     rowptr, ssrc, xwp, dinv, bo, nullptr, outbuf, n);
}

// Round 9
// 232.847 us; speedup vs baseline: 3.9915x; 1.0649x over previous
//
#include <hip/hip_runtime.h>
#include <hip/hip_bf16.h>
#include <hip/hip_fp16.h>
#include <math.h>

typedef _Float16 f16;
typedef __attribute__((ext_vector_type(8))) _Float16 f16x8;
typedef __attribute__((ext_vector_type(4))) float f32x4;

// ---------------- JAX threefry2x32 (partitionable) + normal ----------------

static __device__ __forceinline__ unsigned rotl32(unsigned x, int d) {
  return (x << d) | (x >> (32 - d));
}

// key = (0, 42)  == jax.random.key(42)
static __device__ __forceinline__ void threefry_0_42(unsigned& x0, unsigned& x1) {
  const unsigned ks0 = 0u, ks1 = 42u, ks2 = 0u ^ 42u ^ 0x1BD11BDAu;
  x0 += ks0; x1 += ks1;
#define TF_R(r) { x0 += x1; x1 = rotl32(x1, (r)); x1 ^= x0; }
  TF_R(13) TF_R(15) TF_R(26) TF_R(6)
  x0 += ks1; x1 += ks2 + 1u;
  TF_R(17) TF_R(29) TF_R(16) TF_R(24)
  x0 += ks2; x1 += ks0 + 2u;
  TF_R(13) TF_R(15) TF_R(26) TF_R(6)
  x0 += ks0; x1 += ks1 + 3u;
  TF_R(17) TF_R(29) TF_R(16) TF_R(24)
  x0 += ks1; x1 += ks2 + 4u;
  TF_R(13) TF_R(15) TF_R(26) TF_R(6)
  x0 += ks2; x1 += ks0 + 5u;
#undef TF_R
}

static __device__ __forceinline__ float erfinv_f(float u) {
  float w = -logf((1.0f - u) * (1.0f + u));
  float p;
  if (w < 5.0f) {
    w = w - 2.5f;
    p = 2.81022636e-08f;
    p = fmaf(p, w, 3.43273939e-07f);
    p = fmaf(p, w, -3.5233877e-06f);
    p = fmaf(p, w, -4.39150654e-06f);
    p = fmaf(p, w, 0.00021858087f);
    p = fmaf(p, w, -0.00125372503f);
    p = fmaf(p, w, -0.00417768164f);
    p = fmaf(p, w, 0.246640727f);
    p = fmaf(p, w, 1.50140941f);
  } else {
    w = sqrtf(w) - 3.0f;
    p = -0.000200214257f;
    p = fmaf(p, w, 0.000100950558f);
    p = fmaf(p, w, 0.00134934322f);
    p = fmaf(p, w, -0.00367342844f);
    p = fmaf(p, w, 0.00573950773f);
    p = fmaf(p, w, -0.0076224613f);
    p = fmaf(p, w, 0.00943887047f);
    p = fmaf(p, w, 1.00167406f);
    p = fmaf(p, w, 2.83297682f);
  }
  return p * u;
}

// jax_threefry_partitionable=True: bits(j) = xor(threefry2x32(key, (0, j)))
static __device__ __forceinline__ float jax_normal_at(unsigned j) {
  unsigned x0 = 0u, x1 = j;
  threefry_0_42(x0, x1);
  unsigned bits = x0 ^ x1;
  float f = __uint_as_float((bits >> 9) | 0x3f800000u) - 1.0f;   // [0,1)
  float u = fmaf(f, 1.99999994f, -0.99999994f);
  return 1.41421356237f * erfinv_f(u);
}

// ---------------- setup kernels ----------------

__global__ void zero_i_kernel(int* __restrict__ p, int n) {
  int i = blockIdx.x * blockDim.x + threadIdx.x;
  if (i < n) p[i] = 0;
}

__global__ void degree_i_kernel(const int* __restrict__ dstI, int* __restrict__ cnt, int ne) {
  int e = blockIdx.x * blockDim.x + threadIdx.x;
  if (e < ne) atomicAdd(&cnt[dstI[e]], 1);
}

// ---- exclusive scan of cnt[n] -> rowptr ----
__global__ __launch_bounds__(256) void scan1_kernel(const int* __restrict__ cnt,
                                                    int* __restrict__ rowptr,
                                                    int* __restrict__ bsum, int n) {
  __shared__ int s[256];
  const int t = threadIdx.x;
  const int base = blockIdx.x * 1024 + t * 4;
  int v0, v1, v2, v3;
  if (base + 3 < n) {
    int4 v = *(const int4*)(cnt + base);
    v0 = v.x; v1 = v.y; v2 = v.z; v3 = v.w;
  } else {
    v0 = (base + 0 < n) ? cnt[base + 0] : 0;
    v1 = (base + 1 < n) ? cnt[base + 1] : 0;
    v2 = (base + 2 < n) ? cnt[base + 2] : 0;
    v3 = (base + 3 < n) ? cnt[base + 3] : 0;
  }
  int tot = v0 + v1 + v2 + v3;
  s[t] = tot;
  __syncthreads();
  for (int off = 1; off < 256; off <<= 1) {
    int x = (t >= off) ? s[t - off] : 0;
    __syncthreads();
    s[t] += x;
    __syncthreads();
  }
  int excl = s[t] - tot;
  if (t == 255) bsum[blockIdx.x] = s[t];
  if (base + 0 < n) rowptr[base + 0] = excl;
  if (base + 1 < n) rowptr[base + 1] = excl + v0;
  if (base + 2 < n) rowptr[base + 2] = excl + v0 + v1;
  if (base + 3 < n) rowptr[base + 3] = excl + v0 + v1 + v2;
}

__global__ __launch_bounds__(256) void scanP_kernel(int* __restrict__ bsum,
                                                    int* __restrict__ boff,
                                                    int nb, int* __restrict__ rowptr,
                                                    int n, int ne) {
  __shared__ int s[256];
  const int t = threadIdx.x;
  int v = (t < nb) ? bsum[t] : 0;
  s[t] = v;
  __syncthreads();
  for (int off = 1; off < 256; off <<= 1) {
    int x = (t >= off) ? s[t - off] : 0;
    __syncthreads();
    s[t] += x;
    __syncthreads();
  }
  if (t < nb) boff[t] = s[t] - v;
  if (t == 0) rowptr[n] = ne;
}

// adds block offsets; computes dinv; inits bucket cursors bcur[b] = rowptr[b<<8]
__global__ void scan2_kernel(int* __restrict__ rowptr, const int* __restrict__ boff,
                             const int* __restrict__ cnt, float* __restrict__ dinv,
                             int* __restrict__ bcur, int n) {
  int i = blockIdx.x * blockDim.x + threadIdx.x;
  if (i < n) {
    int rp = rowptr[i] + boff[i >> 10];
    rowptr[i] = rp;
    if ((i & 255) == 0) bcur[i >> 8] = rp;
    float d = (float)cnt[i] + 1.0f;
    dinv[i] = 1.0f / sqrtf(d);
  }
}

// ---------------- two-pass binned fill (kills scatter write amplification) ----------------
// Pass A: bucket = dst>>8. Per 2048-edge block: LDS histogram -> prefix -> stage in
// bucket order -> reserve contiguous global runs via one atomicAdd per bucket ->
// flush runs to coarse[] (packed b<<24 | (dst&255)<<16 | src).
#define EPB 2048
__global__ __launch_bounds__(256) void fillA_kernel(
    const int* __restrict__ srcI, const int* __restrict__ dstI,
    int* __restrict__ bcur, unsigned* __restrict__ coarse, int ne) {
  __shared__ int hist[256], hpre[256], hcur[256], gbase[256];
  __shared__ unsigned st[EPB];
  const int tid = threadIdx.x;
  const int base = blockIdx.x * EPB;

  hist[tid] = 0; hcur[tid] = 0;
  __syncthreads();

  int s[8], d[8];
#pragma unroll
  for (int k = 0; k < 8; ++k) {
    int e = base + k * 256 + tid;          // coalesced per instruction
    if (e < ne) { s[k] = srcI[e]; d[k] = dstI[e]; }
    else        { s[k] = -1;      d[k] = 0; }
  }
#pragma unroll
  for (int k = 0; k < 8; ++k)
    if (s[k] >= 0) atomicAdd(&hist[d[k] >> 8], 1);
  __syncthreads();

  // inclusive prefix of hist into hpre
  int hv = hist[tid];
  hpre[tid] = hv;
  __syncthreads();
  for (int off = 1; off < 256; off <<= 1) {
    int x = (tid >= off) ? hpre[tid - off] : 0;
    __syncthreads();
    hpre[tid] += x;
    __syncthreads();
  }

  // stage edges in bucket order (exclusive base = hpre[b]-hist[b])
#pragma unroll
  for (int k = 0; k < 8; ++k) {
    if (s[k] >= 0) {
      int b = d[k] >> 8;
      int pos = (hpre[b] - hist[b]) + atomicAdd(&hcur[b], 1);
      st[pos] = ((unsigned)b << 24) | ((unsigned)(d[k] & 255) << 16) | (unsigned)s[k];
    }
  }
  // reserve global runs
  if (hist[tid] > 0) gbase[tid] = atomicAdd(&bcur[tid], hist[tid]);
  __syncthreads();

  int cntE = ne - base; if (cntE > EPB) cntE = EPB;
  for (int i = tid; i < cntE; i += 256) {
    unsigned v = st[i];
    int b = v >> 24;
    int excl = hpre[b] - hist[b];
    coarse[gbase[b] + (i - excl)] = v & 0x00FFFFFFu;
  }
}

// Pass B: one block per bucket; block owns ssrc[rowptr[b<<8] .. rowptr[(b+1)<<8]) exclusively.
__global__ __launch_bounds__(256) void fillB_kernel(
    const unsigned* __restrict__ coarse, const int* __restrict__ rowptr,
    unsigned short* __restrict__ ssrc, int n, int ne) {
  __shared__ int rcur[256];
  const int b = blockIdx.x;
  const int r0 = b << 8;
  const int tid = threadIdx.x;
  if (r0 + tid < n) rcur[tid] = rowptr[r0 + tid];
  const int e0 = rowptr[r0];
  const int e1 = (r0 + 256 <= n) ? rowptr[r0 + 256] : ne;
  __syncthreads();
  for (int e = e0 + tid; e < e1; e += 256) {
    unsigned v = coarse[e];
    int r = (v >> 16) & 255;
    int pos = atomicAdd(&rcur[r], 1);
    ssrc[pos] = (unsigned short)(v & 0xFFFFu);
  }
}

// ---------------- MFMA GEMM: Y[n][64] = fp16(concat(X1,X2)) @ fp16(W) * dinv ----------------
// 128 nodes/block, 4 waves; wave = 32 rows x 64 cols; K-step 32 via mfma_f32_16x16x32_f16.
template<int IN1, int IN2, bool X1HALF, bool DUALW>
__global__ __launch_bounds__(256) void gemm_mfma_kernel(
    const void* __restrict__ X1v, const float* __restrict__ X2,
    const float* __restrict__ Wa, const float* __restrict__ Wb,
    const float* __restrict__ dinv, __half* __restrict__ Y, int n) {
  constexpr int IN = IN1 + IN2;
  constexpr int IP = IN + 8;
  __shared__ f16 xs[128 * IP];
  __shared__ f16 wt[64 * IP];  // W transposed: wt[col][k]

  const int tid = threadIdx.x;
  const int base = blockIdx.x * 128;

  for (int i = tid; i < IN * 64; i += 256) {
    int k = i >> 6, c = i & 63;
    float w;
    if (DUALW) w = (c < 32) ? Wa[k * 32 + c] : Wb[k * 32 + (c - 32)];
    else       w = Wa[i];
    wt[c * IP + k] = (f16)w;
  }
  if (X1HALF) {
    const __half* X1 = (const __half*)X1v;
    for (int idx = tid; idx < 128 * (IN1 / 8); idx += 256) {
      int node = idx / (IN1 / 8);
      int k8 = (idx % (IN1 / 8)) * 8;
      int g = base + node;
      f16x8 v = {};
      if (g < n) v = *(const f16x8*)(X1 + (size_t)g * IN1 + k8);
      *(f16x8*)&xs[node * IP + k8] = v;
    }
  } else {
    const float* X1 = (const float*)X1v;
    for (int idx = tid; idx < 128 * (IN1 / 4); idx += 256) {
      int node = idx / (IN1 / 4);
      int k4 = (idx % (IN1 / 4)) * 4;
      int g = base + node;
      float4 v = (g < n) ? *(const float4*)(X1 + (size_t)g * IN1 + k4)
                         : make_float4(0.f, 0.f, 0.f, 0.f);
      f16* p = &xs[node * IP + k4];
      p[0] = (f16)v.x; p[1] = (f16)v.y; p[2] = (f16)v.z; p[3] = (f16)v.w;
    }
  }
  if (IN2 > 0) {
    for (int idx = tid; idx < 128 * (IN2 / 4); idx += 256) {
      int node = idx / (IN2 / 4);
      int k4 = (idx % (IN2 / 4)) * 4;
      int g = base + node;
      float4 v = (g < n) ? *(const float4*)(X2 + (size_t)g * IN2 + k4)
                         : make_float4(0.f, 0.f, 0.f, 0.f);
      f16* p = &xs[node * IP + IN1 + k4];
      p[0] = (f16)v.x; p[1] = (f16)v.y; p[2] = (f16)v.z; p[3] = (f16)v.w;
    }
  }
  __syncthreads();

  const int wid  = tid >> 6;
  const int lane = tid & 63;
  const int l15  = lane & 15;
  const int lk8  = (lane >> 4) * 8;

  f32x4 acc[2][4] = {{{0.f,0.f,0.f,0.f}}};
  constexpr int KB = IN / 32;
#pragma unroll
  for (int kb = 0; kb < KB; ++kb) {
    const int k0 = kb * 32 + lk8;
    f16x8 a0 = *(const f16x8*)&xs[(wid * 32 +      l15) * IP + k0];
    f16x8 a1 = *(const f16x8*)&xs[(wid * 32 + 16 + l15) * IP + k0];
#pragma unroll
    for (int ct = 0; ct < 4; ++ct) {
      f16x8 b = *(const f16x8*)&wt[(ct * 16 + l15) * IP + k0];
      acc[0][ct] = __builtin_amdgcn_mfma_f32_16x16x32_f16(a0, b, acc[0][ct], 0, 0, 0);
      acc[1][ct] = __builtin_amdgcn_mfma_f32_16x16x32_f16(a1, b, acc[1][ct], 0, 0, 0);
    }
  }

#pragma unroll
  for (int rt = 0; rt < 2; ++rt) {
#pragma unroll
    for (int i = 0; i < 4; ++i) {
      int node = base + wid * 32 + rt * 16 + (lane >> 4) * 4 + i;
      if (node < n) {
        float dv = dinv[node];
#pragma unroll
        for (int ct = 0; ct < 4; ++ct) {
          Y[(size_t)node * 64 + ct * 16 + l15] = __float2half(acc[rt][ct][i] * dv);
        }
      }
    }
  }
}

// ---------------- CSR gather + fused finalize (half2 lanes, 8-deep ILP) ----------------
// MODE 0: +bias, relu -> __half out. MODE 1: mean||logvar -> z/mean/logvar (fp32).
// MODE 2: +bias -> fp32 out.
template<int MODE>
__global__ __launch_bounds__(256) void gather_kernel(
    const int* __restrict__ rowptr, const unsigned short* __restrict__ ssrc,
    const __half* __restrict__ xwp, const float* __restrict__ dinv,
    const float* __restrict__ b0, const float* __restrict__ b1,
    void* __restrict__ outv, int n) {
  const int node = (blockIdx.x * 256 + threadIdx.x) >> 6;
  const int lane = threadIdx.x & 63;
  if (node >= n) return;
  const int hf = lane >> 5;
  const int cl = lane & 31;

  float2 a1, a2, a3, a4;
  a2.x = a2.y = a3.x = a3.y = a4.x = a4.y = 0.f;
  {
    float2 f = __half22float2(((const __half2*)(xwp + (size_t)node * 64))[cl]);
    a1.x = hf ? 0.f : f.x;
    a1.y = hf ? 0.f : f.y;
  }

  const int beg = rowptr[node];
  const int end = rowptr[node + 1];
  for (int cbase = beg; cbase < end; cbase += 64) {
    int m = end - cbase; if (m > 64) m = 64;
    unsigned sv = (lane < m) ? (unsigned)ssrc[cbase + lane] : 0u;
    int k = 0;
    for (; k + 7 < m; k += 8) {
      unsigned sa = __shfl(sv, k + 0 + hf, 64);
      unsigned sb = __shfl(sv, k + 2 + hf, 64);
      unsigned sc = __shfl(sv, k + 4 + hf, 64);
      unsigned sd = __shfl(sv, k + 6 + hf, 64);
      float2 fa = __half22float2(((const __half2*)(xwp + (size_t)sa * 64))[cl]);
      float2 fb = __half22float2(((const __half2*)(xwp + (size_t)sb * 64))[cl]);
      float2 fc = __half22float2(((const __half2*)(xwp + (size_t)sc * 64))[cl]);
      float2 fd = __half22float2(((const __half2*)(xwp + (size_t)sd * 64))[cl]);
      a1.x += fa.x; a1.y += fa.y;
      a2.x += fb.x; a2.y += fb.y;
      a3.x += fc.x; a3.y += fc.y;
      a4.x += fd.x; a4.y += fd.y;
    }
    for (; k + 1 < m; k += 2) {
      unsigned sa = __shfl(sv, k + hf, 64);
      float2 fa = __half22float2(((const __half2*)(xwp + (size_t)sa * 64))[cl]);
      a1.x += fa.x; a1.y += fa.y;
    }
    if (k < m) {
      unsigned sa = __shfl(sv, k, 64);
      if (hf == 0) {
        float2 fa = __half22float2(((const __half2*)(xwp + (size_t)sa * 64))[cl]);
        a1.x += fa.x; a1.y += fa.y;
      }
    }
  }
  float2 acc;
  acc.x = (a1.x + a2.x) + (a3.x + a4.x);
  acc.y = (a1.y + a2.y) + (a3.y + a4.y);
  acc.x += __shfl(acc.x, lane ^ 32, 64);
  acc.y += __shfl(acc.y, lane ^ 32, 64);
  float dv = dinv[node];
  float vx = acc.x * dv, vy = acc.y * dv;

  if (hf != 0) return;

  const int c0 = 2 * cl;
  if (MODE == 0) {
    __half* out = (__half*)outv;
    __half2 o = __floats2half2_rn(fmaxf(vx + b0[c0], 0.0f), fmaxf(vy + b0[c0 + 1], 0.0f));
    ((__half2*)(out + (size_t)node * 64))[cl] = o;
  } else if (MODE == 2) {
    float* out = (float*)outv;
    float2 o;
    o.x = vx + b0[c0];
    o.y = vy + b0[c0 + 1];
    ((float2*)(out + (size_t)node * 64))[cl] = o;
  } else {
    float* out = (float*)outv;
    float bx = (c0 < 32) ? b0[c0] : b1[c0 - 32];
    float by = (c0 + 1 < 32) ? b0[c0 + 1] : b1[c0 + 1 - 32];
    vx += bx; vy += by;
    float ox = __shfl(vx, lane + 16, 64);
    float oy = __shfl(vy, lane + 16, 64);
    const int NZ = n * 32;
    if (cl < 16) {
      int j = node * 32 + c0;
      float n0 = jax_normal_at((unsigned)j);
      float n1 = jax_normal_at((unsigned)(j + 1));
      out[j]     = fmaf(n0, expf(0.5f * ox), vx);  // z
      out[j + 1] = fmaf(n1, expf(0.5f * oy), vy);
      out[NZ + j]     = vx;                        // mean
      out[NZ + j + 1] = vy;
    } else {
      int j = node * 32 + (c0 - 32);
      out[2 * NZ + j]     = vx;                    // logvar
      out[2 * NZ + j + 1] = vy;
    }
  }
}

// ---------------- launch ----------------

extern "C" void kernel_launch(void* const* d_in, const int* in_sizes, int n_in,
                              void* d_out, int out_size, void* d_ws, size_t ws_size,
                              hipStream_t stream) {
  const float* feat = (const float*)d_in[0];
  const float* cond = (const float*)d_in[1];
  const int*   eidx = (const int*)d_in[2];
  const float* W1  = (const float*)d_in[3];
  const float* b1  = (const float*)d_in[4];
  const float* Wm  = (const float*)d_in[5];
  const float* bm  = (const float*)d_in[6];
  const float* Wlv = (const float*)d_in[7];
  const float* blv = (const float*)d_in[8];
  const float* Wd  = (const float*)d_in[9];
  const float* bd  = (const float*)d_in[10];
  const float* Wo  = (const float*)d_in[11];
  const float* bo  = (const float*)d_in[12];

  const int n  = in_sizes[0] / 64;   // 50000 (< 65536 -> ssrc/src pack in 16 bits)
  const int ne = in_sizes[2] / 2;    // 800000
  const int* srcI = eidx;
  const int* dstI = eidx + ne;
  const int nbuck = (n + 255) >> 8;  // 196

  // workspace carve-up
  int*   cnt    = (int*)d_ws;                     // n
  int*   rowptr = cnt + n;                        // n+1
  int*   bsum   = rowptr + n + 1;                 // 256
  int*   boff   = bsum + 256;                     // 256
  int*   bcur   = boff + 256;                     // 256
  float* dinv   = (float*)(bcur + 256 + 3);       // n
  __half* xwp   = (__half*)(dinv + n);            // n*64
  __half* h     = xwp + (size_t)n * 64;           // n*64
  unsigned short* ssrc = (unsigned short*)(h + (size_t)n * 64); // ne
  unsigned* coarse = (unsigned*)(ssrc + ne + (ne & 1));         // ne

  float* dout   = (float*)d_out;
  float* zbuf   = dout;                        // n*32
  float* outbuf = dout + (size_t)3 * n * 32;   // n*64

  const int BT = 256;
  auto blk = [](long long t) { return (int)((t + 255) / 256); };
  const int nb_n  = blk(n);
  const int nb_e  = blk(ne);
  const int nb_sc = (n + 1023) / 1024;
  const int nb_gw = blk((long long)n * 64);
  const int nb_g  = (n + 127) / 128;
  const int nb_fa = (ne + EPB - 1) / EPB;

  // ---- CSR setup ----
  hipLaunchKernelGGL(zero_i_kernel, dim3(nb_n), dim3(BT), 0, stream, cnt, n);
  hipLaunchKernelGGL(degree_i_kernel, dim3(nb_e), dim3(BT), 0, stream, dstI, cnt, ne);
  hipLaunchKernelGGL(scan1_kernel, dim3(nb_sc), dim3(BT), 0, stream, cnt, rowptr, bsum, n);
  hipLaunchKernelGGL(scanP_kernel, dim3(1), dim3(BT), 0, stream, bsum, boff, nb_sc, rowptr, n, ne);
  hipLaunchKernelGGL(scan2_kernel, dim3(nb_n), dim3(BT), 0, stream, rowptr, boff, cnt, dinv, bcur, n);
  hipLaunchKernelGGL(fillA_kernel, dim3(nb_fa), dim3(BT), 0, stream, srcI, dstI, bcur, coarse, ne);
  hipLaunchKernelGGL(fillB_kernel, dim3(nbuck), dim3(BT), 0, stream, coarse, rowptr, ssrc, n, ne);

  // ---- encoder conv1: h = relu(gcn(concat(feat,cond), W1, b1)) ----
  hipLaunchKernelGGL((gemm_mfma_kernel<64, 32, false, false>), dim3(nb_g), dim3(BT), 0, stream,
                     feat, cond, W1, nullptr, dinv, xwp, n);
  hipLaunchKernelGGL((gather_kernel<0>), dim3(nb_gw), dim3(BT), 0, stream,
                     rowptr, ssrc, xwp, dinv, b1, nullptr, h, n);

  // ---- mean/logvar packed conv + reparam z ----
  hipLaunchKernelGGL((gemm_mfma_kernel<64, 0, true, true>), dim3(nb_g), dim3(BT), 0, stream,
                     h, nullptr, Wm, Wlv, dinv, xwp, n);
  hipLaunchKernelGGL((gather_kernel<1>), dim3(nb_gw), dim3(BT), 0, stream,
                     rowptr, ssrc, xwp, dinv, bm, blv, dout, n);

  // ---- decoder conv1: hd = relu(gcn(concat(z,cond), Wd, bd)) ----
  hipLaunchKernelGGL((gemm_mfma_kernel<32, 32, false, false>), dim3(nb_g), dim3(BT), 0, stream,
                     zbuf, cond, Wd, nullptr, dinv, xwp, n);
  hipLaunchKernelGGL((gather_kernel<0>), dim3(nb_gw), dim3(BT), 0, stream,
                     rowptr, ssrc, xwp, dinv, bd, nullptr, h, n);

  // ---- decoder out conv ----
  hipLaunchKernelGGL((gemm_mfma_kernel<64, 0, true, false>), dim3(nb_g), dim3(BT), 0, stream,
                     h, nullptr, Wo, nullptr, dinv, xwp, n);
  hipLaunchKernelGGL((gather_kernel<2>), dim3(nb_gw), dim3(BT), 0, stream,
                     rowptr, ssrc, xwp, dinv, bo, nullptr, outbuf, n);
}